// Round 1
// baseline (3499.400 us; speedup 1.0000x reference)
//
#include <hip/hip_runtime.h>

#define NRAYS_DEF 8192
#define ACT_SHIFT (-4.5951198501345898f)   // log(1/(1-0.01) - 1)
#define DELTA 0.5f
#define CSTRIDE 4096000                     // 160*160*160
#define XS 25600                            // 160*160
#define YS 160

__device__ __forceinline__ float softplusf(float x) {
    return x > 20.f ? x : log1pf(expf(x));
}
__device__ __forceinline__ unsigned short f2b(float x) {
    unsigned int u = __float_as_uint(x);
    u += 0x7fffu + ((u >> 16) & 1u);
    return (unsigned short)(u >> 16);
}
__device__ __forceinline__ float b2f(unsigned short b) {
    return __uint_as_float(((unsigned int)b) << 16);
}

__device__ __forceinline__ void trisetup(float px, float py, float pz,
                                         int& ix, int& iy, int& iz,
                                         float& fx, float& fy, float& fz) {
    float sx = (px + 1.f) * 0.5f * 159.f;
    float sy = (py + 1.f) * 0.5f * 159.f;
    float sz = (pz + 1.f) * 0.5f * 159.f;
    sx = fminf(fmaxf(sx, 0.f), 159.f);
    sy = fminf(fmaxf(sy, 0.f), 159.f);
    sz = fminf(fmaxf(sz, 0.f), 159.f);
    ix = (int)sx; if (ix > 158) ix = 158;
    iy = (int)sy; if (iy > 158) iy = 158;
    iz = (int)sz; if (iz > 158) iz = 158;
    fx = sx - (float)ix;
    fy = sy - (float)iy;
    fz = sz - (float)iz;
}

// Kernel 1: per-point density -> alpha, log(1-alpha)
__global__ void k_density(const float* __restrict__ dg, const float* __restrict__ xyz,
                          float* __restrict__ alpha, float* __restrict__ log1ma, int M) {
    int i = blockIdx.x * blockDim.x + threadIdx.x;
    if (i >= M) return;
    int ix, iy, iz; float fx, fy, fz;
    trisetup(xyz[3*i], xyz[3*i+1], xyz[3*i+2], ix, iy, iz, fx, fy, fz);
    const float* g = dg + ix * XS + iy * YS + iz;
    float gx = 1.f - fx, gy = 1.f - fy, gz = 1.f - fz;
    float v =
        gx * (gy * (gz * g[0]      + fz * g[1])      + fy * (gz * g[YS]      + fz * g[YS+1])) +
        fx * (gy * (gz * g[XS]     + fz * g[XS+1])   + fy * (gz * g[XS+YS]   + fz * g[XS+YS+1]));
    float sp = softplusf(v + ACT_SHIFT);
    float l  = -sp * DELTA;
    alpha[i]  = 1.f - expf(l);
    log1ma[i] = fmaxf(l, -15.9424285f);   // log1p(-(1-1e-7)) in f32; never triggers for this data
}

// Kernel 2: ray segment starts via binary search (ray_id sorted). starts[NRAYS]=M.
__global__ void k_starts(const int* __restrict__ rid, int* __restrict__ starts, int M, int R) {
    int r = blockIdx.x * blockDim.x + threadIdx.x;
    if (r > R) return;
    int lo = 0, hi = M;
    while (lo < hi) { int mid = (lo + hi) >> 1; if (rid[mid] < r) lo = mid + 1; else hi = mid; }
    starts[r] = lo;
}

// Kernel 3: per-ray view-direction positional encoding table [R][27]
__global__ void k_vdemb(const float* __restrict__ vd, float* __restrict__ emb, int R) {
    int r = blockIdx.x * blockDim.x + threadIdx.x;
    if (r >= R) return;
    float* e = emb + 27 * r;
    float v0 = vd[3*r], v1 = vd[3*r+1], v2 = vd[3*r+2];
    e[0] = v0; e[1] = v1; e[2] = v2;
    float v[3] = {v0, v1, v2};
    #pragma unroll
    for (int d = 0; d < 3; d++) {
        #pragma unroll
        for (int p = 0; p < 4; p++) {
            float a = v[d] * (float)(1 << p);
            e[3 + d*4 + p]  = sinf(a);
            e[15 + d*4 + p] = cosf(a);
        }
    }
}

// Kernel 4: per-ray serial scan -> weights, and out = alphainv_last (base value)
__global__ void k_scan(const float* __restrict__ alpha, const float* __restrict__ log1ma,
                       const int* __restrict__ starts, float* __restrict__ weights,
                       float* __restrict__ out, int R) {
    int r = blockIdx.x * blockDim.x + threadIdx.x;
    if (r >= R) return;
    int s = starts[r], e = starts[r + 1];
    float c = 0.f;
    for (int i = s; i < e; ++i) {
        weights[i] = alpha[i] * expf(c);
        c += log1ma[i];
    }
    float ainv = expf(c);
    out[3*r] = ainv; out[3*r+1] = ainv; out[3*r+2] = ainv;
}

// Kernel 5: per-point 12-ch trilinear gather + MLP + sigmoid + weighted atomic accumulate
__global__ __launch_bounds__(128) void k_mlp(
    const float* __restrict__ k0, const float* __restrict__ xyz,
    const int* __restrict__ rid, const float* __restrict__ vemb,
    const float* __restrict__ weights,
    const float* __restrict__ W0, const float* __restrict__ b0,
    const float* __restrict__ W1, const float* __restrict__ b1,
    const float* __restrict__ W2, const float* __restrict__ b2,
    float* __restrict__ out, int M) {

    __shared__ float feat[128][37];            // stride 37 words: bank=(5t+k)%32, conflict-free
    __shared__ unsigned short h0[128][130];    // stride 130 u16:  bank=(t+(k>>1))%32, conflict-free

    const int t = threadIdx.x;
    const int i = blockIdx.x * 128 + t;
    if (i >= M) return;

    int ix, iy, iz; float fx, fy, fz;
    trisetup(xyz[3*i], xyz[3*i+1], xyz[3*i+2], ix, iy, iz, fx, fy, fz);
    float gx = 1.f - fx, gy = 1.f - fy, gz = 1.f - fz;
    float w000 = gx*gy*gz, w001 = gx*gy*fz, w010 = gx*fy*gz, w011 = gx*fy*fz;
    float w100 = fx*gy*gz, w101 = fx*gy*fz, w110 = fx*fy*gz, w111 = fx*fy*fz;
    const float* gp = k0 + ix * XS + iy * YS + iz;

    float diff[3];
    #pragma unroll
    for (int c = 0; c < 12; c++) {
        const float* g = gp + c * CSTRIDE;
        float v = w000*g[0]    + w001*g[1]     + w010*g[YS]    + w011*g[YS+1]
                + w100*g[XS]   + w101*g[XS+1]  + w110*g[XS+YS] + w111*g[XS+YS+1];
        if (c < 3) diff[c] = v; else feat[t][c-3] = v;
    }

    const int r = rid[i];
    const float* e = vemb + 27 * r;
    #pragma unroll
    for (int k = 0; k < 27; k++) feat[t][9+k] = e[k];

    // layer 1: 36 -> 128 (relu), h0 staged in LDS as bf16
    for (int jc = 0; jc < 128; jc += 64) {
        float acc[64];
        #pragma unroll
        for (int j = 0; j < 64; j++) acc[j] = b0[jc + j];
        for (int k = 0; k < 36; k++) {
            float fk = feat[t][k];
            const float* w = W0 + k * 128 + jc;
            #pragma unroll
            for (int j = 0; j < 64; j++) acc[j] = fmaf(fk, w[j], acc[j]);
        }
        #pragma unroll
        for (int j = 0; j < 64; j++) h0[t][jc + j] = f2b(fmaxf(acc[j], 0.f));
    }

    // layer 2: 128 -> 128 (relu), fused into layer 3: 128 -> 3
    float lg0 = b2[0] + diff[0];
    float lg1 = b2[1] + diff[1];
    float lg2 = b2[2] + diff[2];
    for (int jc = 0; jc < 128; jc += 64) {
        float acc[64];
        #pragma unroll
        for (int j = 0; j < 64; j++) acc[j] = b1[jc + j];
        for (int k = 0; k < 128; k++) {
            float hk = b2f(h0[t][k]);
            const float* w = W1 + k * 128 + jc;
            #pragma unroll
            for (int j = 0; j < 64; j++) acc[j] = fmaf(hk, w[j], acc[j]);
        }
        const float* w2 = W2 + jc * 3;
        #pragma unroll
        for (int j = 0; j < 64; j++) {
            float hk = fmaxf(acc[j], 0.f);
            lg0 = fmaf(hk, w2[j*3+0], lg0);
            lg1 = fmaf(hk, w2[j*3+1], lg1);
            lg2 = fmaf(hk, w2[j*3+2], lg2);
        }
    }

    float wgt = weights[i];
    float s0 = wgt / (1.f + expf(-lg0));
    float s1 = wgt / (1.f + expf(-lg1));
    float s2 = wgt / (1.f + expf(-lg2));
    atomicAdd(out + 3*r + 0, s0);
    atomicAdd(out + 3*r + 1, s1);
    atomicAdd(out + 3*r + 2, s2);
}

extern "C" void kernel_launch(void* const* d_in, const int* in_sizes, int n_in,
                              void* d_out, int out_size, void* d_ws, size_t ws_size,
                              hipStream_t stream) {
    const float* dg  = (const float*)d_in[0];
    const float* k0  = (const float*)d_in[1];
    const float* xyz = (const float*)d_in[2];
    const float* vd  = (const float*)d_in[3];
    const float* W0  = (const float*)d_in[4];
    const float* b0  = (const float*)d_in[5];
    const float* W1  = (const float*)d_in[6];
    const float* b1  = (const float*)d_in[7];
    const float* W2  = (const float*)d_in[8];
    const float* b2  = (const float*)d_in[9];
    const int*   rid = (const int*)d_in[10];
    float* out = (float*)d_out;

    const int M = in_sizes[2] / 3;
    const int R = in_sizes[3] / 3;

    float* alpha   = (float*)d_ws;
    float* log1ma  = alpha + M;
    float* weights = log1ma + M;
    float* vemb    = weights + M;
    int*   starts  = (int*)(vemb + (size_t)R * 27);

    k_density<<<dim3((M + 255) / 256), dim3(256), 0, stream>>>(dg, xyz, alpha, log1ma, M);
    k_starts <<<dim3((R + 1 + 255) / 256), dim3(256), 0, stream>>>(rid, starts, M, R);
    k_vdemb  <<<dim3((R + 255) / 256), dim3(256), 0, stream>>>(vd, vemb, R);
    k_scan   <<<dim3((R + 255) / 256), dim3(256), 0, stream>>>(alpha, log1ma, starts, weights, out, R);
    k_mlp    <<<dim3((M + 127) / 128), dim3(128), 0, stream>>>(k0, xyz, rid, vemb, weights,
                                                               W0, b0, W1, b1, W2, b2, out, M);
}

// Round 2
// 1219.370 us; speedup vs baseline: 2.8698x; 2.8698x over previous
//
#include <hip/hip_runtime.h>

#define ACT_SHIFT (-4.5951198501345898f)   // log(1/(1-0.01) - 1)
#define DELTA 0.5f
#define CSTRIDE 4096000                     // 160*160*160
#define XS 25600                            // 160*160
#define YS 160
#define NVOX 4096000

typedef __attribute__((ext_vector_type(8))) short short8;
typedef __attribute__((ext_vector_type(4))) float f32x4;
typedef __attribute__((ext_vector_type(2))) unsigned int u32x2;
typedef __attribute__((ext_vector_type(4))) unsigned int u32x4;

__device__ __forceinline__ float softplusf(float x) {
    return x > 20.f ? x : log1pf(expf(x));
}
__device__ __forceinline__ unsigned short f2b(float x) {
    unsigned int u = __float_as_uint(x);
    u += 0x7fffu + ((u >> 16) & 1u);
    return (unsigned short)(u >> 16);
}
__device__ __forceinline__ float blo(unsigned int u) { return __uint_as_float(u << 16); }
__device__ __forceinline__ float bhi(unsigned int u) { return __uint_as_float(u & 0xffff0000u); }

__device__ __forceinline__ void trisetup(float px, float py, float pz,
                                         int& ix, int& iy, int& iz,
                                         float& fx, float& fy, float& fz) {
    float sx = (px + 1.f) * 0.5f * 159.f;
    float sy = (py + 1.f) * 0.5f * 159.f;
    float sz = (pz + 1.f) * 0.5f * 159.f;
    sx = fminf(fmaxf(sx, 0.f), 159.f);
    sy = fminf(fmaxf(sy, 0.f), 159.f);
    sz = fminf(fmaxf(sz, 0.f), 159.f);
    ix = (int)sx; if (ix > 158) ix = 158;
    iy = (int)sy; if (iy > 158) iy = 158;
    iz = (int)sz; if (iz > 158) iz = 158;
    fx = sx - (float)ix;
    fy = sy - (float)iy;
    fz = sz - (float)iz;
}

// --- transpose k0 [12][160^3] f32 -> channel-last bf16 [160^3][12] ---
__global__ void k_t(const float* __restrict__ k0, unsigned short* __restrict__ k0b) {
    int v = blockIdx.x * 256 + threadIdx.x;
    if (v >= NVOX) return;
    unsigned int o[6];
    #pragma unroll
    for (int j = 0; j < 6; j++) {
        unsigned short lo = f2b(k0[(size_t)(2*j)   * NVOX + v]);
        unsigned short hi = f2b(k0[(size_t)(2*j+1) * NVOX + v]);
        o[j] = (unsigned int)lo | ((unsigned int)hi << 16);
    }
    unsigned int* dst = (unsigned int*)((char*)k0b + (size_t)v * 24);
    #pragma unroll
    for (int j = 0; j < 6; j++) dst[j] = o[j];
}

// --- weights -> N-major bf16 (B-fragment friendly), K padded ---
__global__ void k_wprep(const float* __restrict__ W0, const float* __restrict__ W1,
                        const float* __restrict__ W2,
                        unsigned short* __restrict__ Wt0, unsigned short* __restrict__ Wt1,
                        unsigned short* __restrict__ Wt2) {
    int id = blockIdx.x * 256 + threadIdx.x;
    if (id < 128 * 64)  { int n = id >> 6, k = id & 63;  Wt0[id] = (k < 36) ? f2b(W0[k*128 + n]) : 0; }
    if (id < 128 * 128) { int n = id >> 7, k = id & 127; Wt1[id] = f2b(W1[k*128 + n]); }
    if (id < 16 * 128)  { int n = id >> 7, k = id & 127; Wt2[id] = (n < 3) ? f2b(W2[k*3 + n]) : 0; }
}

// --- per-point density -> alpha, log(1-alpha) (f32 path, unchanged) ---
__global__ void k_density(const float* __restrict__ dg, const float* __restrict__ xyz,
                          float* __restrict__ alpha, float* __restrict__ log1ma, int M) {
    int i = blockIdx.x * blockDim.x + threadIdx.x;
    if (i >= M) return;
    int ix, iy, iz; float fx, fy, fz;
    trisetup(xyz[3*i], xyz[3*i+1], xyz[3*i+2], ix, iy, iz, fx, fy, fz);
    const float* g = dg + ix * XS + iy * YS + iz;
    float gx = 1.f - fx, gy = 1.f - fy, gz = 1.f - fz;
    float v =
        gx * (gy * (gz * g[0]      + fz * g[1])      + fy * (gz * g[YS]      + fz * g[YS+1])) +
        fx * (gy * (gz * g[XS]     + fz * g[XS+1])   + fy * (gz * g[XS+YS]   + fz * g[XS+YS+1]));
    float sp = softplusf(v + ACT_SHIFT);
    float l  = -sp * DELTA;
    alpha[i]  = 1.f - expf(l);
    log1ma[i] = fmaxf(l, -15.9424285f);
}

__global__ void k_starts(const int* __restrict__ rid, int* __restrict__ starts, int M, int R) {
    int r = blockIdx.x * blockDim.x + threadIdx.x;
    if (r > R) return;
    int lo = 0, hi = M;
    while (lo < hi) { int mid = (lo + hi) >> 1; if (rid[mid] < r) lo = mid + 1; else hi = mid; }
    starts[r] = lo;
}

// --- per-ray view-dir PE table, bf16 [R][28] (slot 27 = 0 pad) ---
__global__ void k_vdemb(const float* __restrict__ vd, unsigned short* __restrict__ emb, int R) {
    int r = blockIdx.x * blockDim.x + threadIdx.x;
    if (r >= R) return;
    float e[28];
    float v0 = vd[3*r], v1 = vd[3*r+1], v2 = vd[3*r+2];
    e[0] = v0; e[1] = v1; e[2] = v2;
    float v[3] = {v0, v1, v2};
    #pragma unroll
    for (int d = 0; d < 3; d++) {
        #pragma unroll
        for (int p = 0; p < 4; p++) {
            float a = v[d] * (float)(1 << p);
            e[3 + d*4 + p]  = sinf(a);
            e[15 + d*4 + p] = cosf(a);
        }
    }
    e[27] = 0.f;
    unsigned short* o = emb + r * 28;
    #pragma unroll
    for (int j = 0; j < 28; j++) o[j] = f2b(e[j]);
}

__global__ void k_scan(const float* __restrict__ alpha, const float* __restrict__ log1ma,
                       const int* __restrict__ starts, float* __restrict__ weights,
                       float* __restrict__ out, int R) {
    int r = blockIdx.x * blockDim.x + threadIdx.x;
    if (r >= R) return;
    int s = starts[r], e = starts[r + 1];
    float c = 0.f;
    for (int i = s; i < e; ++i) {
        weights[i] = alpha[i] * expf(c);
        c += log1ma[i];
    }
    float ainv = expf(c);
    out[3*r] = ainv; out[3*r+1] = ainv; out[3*r+2] = ainv;
}

// --- fused gather + MFMA MLP + epilogue. 128 points/block, 256 threads ---
__global__ __launch_bounds__(256) void k_mlp2(
    const unsigned short* __restrict__ k0b, const float* __restrict__ xyz,
    const int* __restrict__ rid, const unsigned short* __restrict__ vemb,
    const float* __restrict__ wts,
    const unsigned short* __restrict__ Wt0, const float* __restrict__ b0,
    const unsigned short* __restrict__ Wt1, const float* __restrict__ b1,
    const unsigned short* __restrict__ Wt2, const float* __restrict__ b2,
    float* __restrict__ out, int M) {

    // feat: 128 rows x 128B (64 bf16, K-padded), XOR-swizzled
    // h   : 128 rows x 256B (128 bf16), XOR-swizzled
    __shared__ char featL[128 * 128];
    __shared__ char hL[128 * 256];
    __shared__ float diffL[128 * 3];
    __shared__ float wgtL[128];
    __shared__ int   ridL[128];

    const int t = threadIdx.x;
    const int base = blockIdx.x * 128;

    if (t < 128) {
        const int i = base + t;
        unsigned int fr[32];
        #pragma unroll
        for (int j = 0; j < 32; j++) fr[j] = 0u;
        float ch[12];
        #pragma unroll
        for (int c = 0; c < 12; c++) ch[c] = 0.f;
        float wpt = 0.f; int r = 0;

        if (i < M) {
            int ix, iy, iz; float fx, fy, fz;
            trisetup(xyz[3*i], xyz[3*i+1], xyz[3*i+2], ix, iy, iz, fx, fy, fz);
            float gx = 1.f - fx, gy = 1.f - fy, gz = 1.f - fz;
            float wxy[4] = {gx*gy, gx*fy, fx*gy, fx*fy};
            #pragma unroll
            for (int s = 0; s < 4; s++) {
                int dx = s >> 1, dy = s & 1;
                const char* p = (const char*)k0b + ((size_t)((ix+dx)*160 + (iy+dy)) * 160 + iz) * 24;
                unsigned int sv[12];
                *(u32x2*)(sv + 0)  = *(const u32x2*)(p);
                *(u32x2*)(sv + 2)  = *(const u32x2*)(p + 8);
                *(u32x2*)(sv + 4)  = *(const u32x2*)(p + 16);
                *(u32x2*)(sv + 6)  = *(const u32x2*)(p + 24);
                *(u32x2*)(sv + 8)  = *(const u32x2*)(p + 32);
                *(u32x2*)(sv + 10) = *(const u32x2*)(p + 40);
                float ws = wxy[s];
                #pragma unroll
                for (int j = 0; j < 6; j++) {
                    ch[2*j]   += ws * (gz * blo(sv[j]) + fz * blo(sv[j+6]));
                    ch[2*j+1] += ws * (gz * bhi(sv[j]) + fz * bhi(sv[j+6]));
                }
            }
            r = rid[i];
            wpt = wts[i];
            // feat[0..8] = k0 channels 3..11
            #pragma unroll
            for (int c = 0; c < 9; c++) {
                int k = c;
                fr[k >> 1] |= ((unsigned int)f2b(ch[3 + c])) << (16 * (k & 1));
            }
            // feat[9..35] = vemb[r][0..26]
            const unsigned int* vp = (const unsigned int*)(vemb + (size_t)r * 28);
            unsigned int ve[14];
            #pragma unroll
            for (int j = 0; j < 14; j++) ve[j] = vp[j];
            #pragma unroll
            for (int j = 0; j < 27; j++) {
                unsigned int val = (ve[j >> 1] >> (16 * (j & 1))) & 0xffffu;
                int k = 9 + j;
                fr[k >> 1] |= val << (16 * (k & 1));
            }
        }
        diffL[t*3 + 0] = ch[0];
        diffL[t*3 + 1] = ch[1];
        diffL[t*3 + 2] = ch[2];
        wgtL[t] = wpt;
        ridL[t] = r;
        {
            char* fp = featL + t * 128;
            unsigned int rs = (unsigned int)((t & 7) << 4);
            #pragma unroll
            for (int j = 0; j < 8; j++)
                *(u32x4*)(fp + ((16u*j) ^ rs)) = *(u32x4*)(fr + 4*j);
        }
    }
    __syncthreads();

    const int lane = t & 63;
    const int w = t >> 6;
    const int g = lane >> 4;
    const int ln = lane & 15;

    // ---- layer 1: feat[128x64] @ Wt0 -> h[128x128] (relu, bf16) ----
    #pragma unroll
    for (int mi = 0; mi < 2; mi++) {
        const int m0 = 32*w + 16*mi;
        const int arow = m0 + ln;
        const unsigned int aswz = (unsigned int)((arow & 7) << 4);
        const char* ab = featL + arow * 128;
        short8 a0 = *(const short8*)(ab + ((16u*g)        ^ aswz));
        short8 a1 = *(const short8*)(ab + ((64u + 16u*g)  ^ aswz));
        #pragma unroll
        for (int nt = 0; nt < 8; nt++) {
            const int n0 = 16 * nt;
            float bias = b0[n0 + ln];
            f32x4 acc = {bias, bias, bias, bias};
            const char* wb = (const char*)Wt0 + (n0 + ln) * 128;
            short8 bf0 = *(const short8*)(wb + 16*g);
            short8 bf1 = *(const short8*)(wb + 64 + 16*g);
            acc = __builtin_amdgcn_mfma_f32_16x16x32_bf16(a0, bf0, acc, 0, 0, 0);
            acc = __builtin_amdgcn_mfma_f32_16x16x32_bf16(a1, bf1, acc, 0, 0, 0);
            #pragma unroll
            for (int v = 0; v < 4; v++) {
                int row = m0 + 4*g + v;
                unsigned short hv = f2b(fmaxf(acc[v], 0.f));
                *(unsigned short*)(hL + (((unsigned)(row*256 + (n0+ln)*2)) ^ ((unsigned)((row & 7) << 4)))) = hv;
            }
        }
    }

    // ---- layer 2: h[128x128] @ Wt1 -> h2 (relu, bf16, in place: wave-private rows) ----
    #pragma unroll
    for (int mi = 0; mi < 2; mi++) {
        const int m0 = 32*w + 16*mi;
        const int arow = m0 + ln;
        const unsigned int aswz = (unsigned int)((arow & 7) << 4);
        const char* ab = hL + arow * 256;
        short8 a0 = *(const short8*)(ab + ((16u*g)         ^ aswz));
        short8 a1 = *(const short8*)(ab + ((64u  + 16u*g)  ^ aswz));
        short8 a2 = *(const short8*)(ab + ((128u + 16u*g)  ^ aswz));
        short8 a3 = *(const short8*)(ab + ((192u + 16u*g)  ^ aswz));
        #pragma unroll
        for (int nt = 0; nt < 8; nt++) {
            const int n0 = 16 * nt;
            float bias = b1[n0 + ln];
            f32x4 acc = {bias, bias, bias, bias};
            const char* wb = (const char*)Wt1 + (n0 + ln) * 256;
            acc = __builtin_amdgcn_mfma_f32_16x16x32_bf16(a0, *(const short8*)(wb + 16*g),       acc, 0, 0, 0);
            acc = __builtin_amdgcn_mfma_f32_16x16x32_bf16(a1, *(const short8*)(wb + 64 + 16*g),  acc, 0, 0, 0);
            acc = __builtin_amdgcn_mfma_f32_16x16x32_bf16(a2, *(const short8*)(wb + 128 + 16*g), acc, 0, 0, 0);
            acc = __builtin_amdgcn_mfma_f32_16x16x32_bf16(a3, *(const short8*)(wb + 192 + 16*g), acc, 0, 0, 0);
            #pragma unroll
            for (int v = 0; v < 4; v++) {
                int row = m0 + 4*g + v;
                unsigned short hv = f2b(fmaxf(acc[v], 0.f));
                *(unsigned short*)(hL + (((unsigned)(row*256 + (n0+ln)*2)) ^ ((unsigned)((row & 7) << 4)))) = hv;
            }
        }
    }

    // ---- layer 3: h2 @ Wt2 (N=16, cols 0..2 live) + sigmoid + weighted atomic ----
    const float b2c = (ln < 3) ? b2[ln] : 0.f;
    #pragma unroll
    for (int mi = 0; mi < 2; mi++) {
        const int m0 = 32*w + 16*mi;
        const int arow = m0 + ln;
        const unsigned int aswz = (unsigned int)((arow & 7) << 4);
        const char* ab = hL + arow * 256;
        short8 a0 = *(const short8*)(ab + ((16u*g)         ^ aswz));
        short8 a1 = *(const short8*)(ab + ((64u  + 16u*g)  ^ aswz));
        short8 a2 = *(const short8*)(ab + ((128u + 16u*g)  ^ aswz));
        short8 a3 = *(const short8*)(ab + ((192u + 16u*g)  ^ aswz));
        f32x4 acc = {0.f, 0.f, 0.f, 0.f};
        const char* wb = (const char*)Wt2 + ln * 256;
        acc = __builtin_amdgcn_mfma_f32_16x16x32_bf16(a0, *(const short8*)(wb + 16*g),       acc, 0, 0, 0);
        acc = __builtin_amdgcn_mfma_f32_16x16x32_bf16(a1, *(const short8*)(wb + 64 + 16*g),  acc, 0, 0, 0);
        acc = __builtin_amdgcn_mfma_f32_16x16x32_bf16(a2, *(const short8*)(wb + 128 + 16*g), acc, 0, 0, 0);
        acc = __builtin_amdgcn_mfma_f32_16x16x32_bf16(a3, *(const short8*)(wb + 192 + 16*g), acc, 0, 0, 0);
        if (ln < 3) {
            #pragma unroll
            for (int v = 0; v < 4; v++) {
                int row = m0 + 4*g + v;
                float logit = acc[v] + b2c + diffL[row*3 + ln];
                float val = wgtL[row] / (1.f + expf(-logit));
                atomicAdd(out + 3*ridL[row] + ln, val);
            }
        }
    }
}

extern "C" void kernel_launch(void* const* d_in, const int* in_sizes, int n_in,
                              void* d_out, int out_size, void* d_ws, size_t ws_size,
                              hipStream_t stream) {
    const float* dg  = (const float*)d_in[0];
    const float* k0  = (const float*)d_in[1];
    const float* xyz = (const float*)d_in[2];
    const float* vd  = (const float*)d_in[3];
    const float* W0  = (const float*)d_in[4];
    const float* b0  = (const float*)d_in[5];
    const float* W1  = (const float*)d_in[6];
    const float* b1  = (const float*)d_in[7];
    const float* W2  = (const float*)d_in[8];
    const float* b2  = (const float*)d_in[9];
    const int*   rid = (const int*)d_in[10];
    float* out = (float*)d_out;

    const int M = in_sizes[2] / 3;
    const int R = in_sizes[3] / 3;

    char* w = (char*)d_ws;
    unsigned short* k0b  = (unsigned short*)w;  w += (size_t)NVOX * 12 * 2;   // 98.3 MB
    unsigned short* Wt0  = (unsigned short*)w;  w += 128 * 64 * 2;
    unsigned short* Wt1  = (unsigned short*)w;  w += 128 * 128 * 2;
    unsigned short* Wt2  = (unsigned short*)w;  w += 16 * 128 * 2;
    unsigned short* vembb= (unsigned short*)w;  w += (size_t)R * 28 * 2;
    float* alpha   = (float*)w;  w += (size_t)M * 4;
    float* log1ma  = (float*)w;  w += (size_t)M * 4;
    float* wts     = (float*)w;  w += (size_t)M * 4;
    int*   starts  = (int*)w;    w += (size_t)(R + 1) * 4;

    k_t      <<<dim3((NVOX + 255) / 256), dim3(256), 0, stream>>>(k0, k0b);
    k_wprep  <<<dim3(64), dim3(256), 0, stream>>>(W0, W1, W2, Wt0, Wt1, Wt2);
    k_density<<<dim3((M + 255) / 256), dim3(256), 0, stream>>>(dg, xyz, alpha, log1ma, M);
    k_starts <<<dim3((R + 1 + 255) / 256), dim3(256), 0, stream>>>(rid, starts, M, R);
    k_vdemb  <<<dim3((R + 255) / 256), dim3(256), 0, stream>>>(vd, vembb, R);
    k_scan   <<<dim3((R + 255) / 256), dim3(256), 0, stream>>>(alpha, log1ma, starts, wts, out, R);
    k_mlp2   <<<dim3((M + 127) / 128), dim3(256), 0, stream>>>(k0b, xyz, rid, vembb, wts,
                                                               Wt0, b0, Wt1, b1, Wt2, b2, out, M);
}

// Round 3
// 980.437 us; speedup vs baseline: 3.5692x; 1.2437x over previous
//
#include <hip/hip_runtime.h>

#define ACT_SHIFT (-4.5951198501345898f)   // log(1/(1-0.01) - 1)
#define DELTA 0.5f
#define XS 25600                            // 160*160
#define YS 160
#define NVOX 4096000

typedef __attribute__((ext_vector_type(8))) short short8;
typedef __attribute__((ext_vector_type(4))) float f32x4;
typedef __attribute__((ext_vector_type(2))) unsigned int u32x2;
typedef __attribute__((ext_vector_type(4))) unsigned int u32x4;

__device__ __forceinline__ float softplusf(float x) {
    return x > 20.f ? x : log1pf(expf(x));
}
__device__ __forceinline__ unsigned short f2b(float x) {
    unsigned int u = __float_as_uint(x);
    u += 0x7fffu + ((u >> 16) & 1u);
    return (unsigned short)(u >> 16);
}
__device__ __forceinline__ float blo(unsigned int u) { return __uint_as_float(u << 16); }
__device__ __forceinline__ float bhi(unsigned int u) { return __uint_as_float(u & 0xffff0000u); }

__device__ __forceinline__ void trisetup(float px, float py, float pz,
                                         int& ix, int& iy, int& iz,
                                         float& fx, float& fy, float& fz) {
    float sx = (px + 1.f) * 0.5f * 159.f;
    float sy = (py + 1.f) * 0.5f * 159.f;
    float sz = (pz + 1.f) * 0.5f * 159.f;
    sx = fminf(fmaxf(sx, 0.f), 159.f);
    sy = fminf(fmaxf(sy, 0.f), 159.f);
    sz = fminf(fmaxf(sz, 0.f), 159.f);
    ix = (int)sx; if (ix > 158) ix = 158;
    iy = (int)sy; if (iy > 158) iy = 158;
    iz = (int)sz; if (iz > 158) iz = 158;
    fx = sx - (float)ix;
    fy = sy - (float)iy;
    fz = sz - (float)iz;
}

// --- transpose k0 [12][160^3] f32 -> channel-last bf16; PAD16: 32B/voxel, else 24B ---
template<bool PAD16>
__global__ void k_t(const float* __restrict__ k0, unsigned short* __restrict__ k0b) {
    int v = blockIdx.x * 256 + threadIdx.x;
    if (v >= NVOX) return;
    unsigned int o[8];
    o[6] = 0u; o[7] = 0u;
    #pragma unroll
    for (int j = 0; j < 6; j++) {
        unsigned short lo = f2b(k0[(size_t)(2*j)   * NVOX + v]);
        unsigned short hi = f2b(k0[(size_t)(2*j+1) * NVOX + v]);
        o[j] = (unsigned int)lo | ((unsigned int)hi << 16);
    }
    if (PAD16) {
        u32x4* dst = (u32x4*)((char*)k0b + (size_t)v * 32);
        dst[0] = *(u32x4*)(o);
        dst[1] = *(u32x4*)(o + 4);
    } else {
        unsigned int* dst = (unsigned int*)((char*)k0b + (size_t)v * 24);
        #pragma unroll
        for (int j = 0; j < 6; j++) dst[j] = o[j];
    }
}

// --- weights -> N-major bf16 (B-fragment friendly), K padded ---
__global__ void k_wprep(const float* __restrict__ W0, const float* __restrict__ W1,
                        const float* __restrict__ W2,
                        unsigned short* __restrict__ Wt0, unsigned short* __restrict__ Wt1,
                        unsigned short* __restrict__ Wt2) {
    int id = blockIdx.x * 256 + threadIdx.x;
    if (id < 128 * 64)  { int n = id >> 6, k = id & 63;  Wt0[id] = (k < 36) ? f2b(W0[k*128 + n]) : 0; }
    if (id < 128 * 128) { int n = id >> 7, k = id & 127; Wt1[id] = f2b(W1[k*128 + n]); }
    if (id < 16 * 128)  { int n = id >> 7, k = id & 127; Wt2[id] = (n < 3) ? f2b(W2[k*3 + n]) : 0; }
}

__global__ void k_density(const float* __restrict__ dg, const float* __restrict__ xyz,
                          float* __restrict__ alpha, float* __restrict__ log1ma, int M) {
    int i = blockIdx.x * blockDim.x + threadIdx.x;
    if (i >= M) return;
    int ix, iy, iz; float fx, fy, fz;
    trisetup(xyz[3*i], xyz[3*i+1], xyz[3*i+2], ix, iy, iz, fx, fy, fz);
    const float* g = dg + ix * XS + iy * YS + iz;
    float gx = 1.f - fx, gy = 1.f - fy, gz = 1.f - fz;
    float v =
        gx * (gy * (gz * g[0]      + fz * g[1])      + fy * (gz * g[YS]      + fz * g[YS+1])) +
        fx * (gy * (gz * g[XS]     + fz * g[XS+1])   + fy * (gz * g[XS+YS]   + fz * g[XS+YS+1]));
    float sp = softplusf(v + ACT_SHIFT);
    float l  = -sp * DELTA;
    alpha[i]  = 1.f - expf(l);
    log1ma[i] = fmaxf(l, -15.9424285f);
}

__global__ void k_starts(const int* __restrict__ rid, int* __restrict__ starts, int M, int R) {
    int r = blockIdx.x * blockDim.x + threadIdx.x;
    if (r > R) return;
    int lo = 0, hi = M;
    while (lo < hi) { int mid = (lo + hi) >> 1; if (rid[mid] < r) lo = mid + 1; else hi = mid; }
    starts[r] = lo;
}

__global__ void k_vdemb(const float* __restrict__ vd, unsigned short* __restrict__ emb, int R) {
    int r = blockIdx.x * blockDim.x + threadIdx.x;
    if (r >= R) return;
    float e[28];
    float v0 = vd[3*r], v1 = vd[3*r+1], v2 = vd[3*r+2];
    e[0] = v0; e[1] = v1; e[2] = v2;
    float v[3] = {v0, v1, v2};
    #pragma unroll
    for (int d = 0; d < 3; d++) {
        #pragma unroll
        for (int p = 0; p < 4; p++) {
            float a = v[d] * (float)(1 << p);
            e[3 + d*4 + p]  = sinf(a);
            e[15 + d*4 + p] = cosf(a);
        }
    }
    e[27] = 0.f;
    unsigned short* o = emb + r * 28;
    #pragma unroll
    for (int j = 0; j < 28; j++) o[j] = f2b(e[j]);
}

__global__ void k_scan(const float* __restrict__ alpha, const float* __restrict__ log1ma,
                       const int* __restrict__ starts, float* __restrict__ weights,
                       float* __restrict__ out, int R) {
    int r = blockIdx.x * blockDim.x + threadIdx.x;
    if (r >= R) return;
    int s = starts[r], e = starts[r + 1];
    float c = 0.f;
    for (int i = s; i < e; ++i) {
        weights[i] = alpha[i] * expf(c);
        c += log1ma[i];
    }
    float ainv = expf(c);
    out[3*r] = ainv; out[3*r+1] = ainv; out[3*r+2] = ainv;
}

// --- fused gather + MFMA MLP + reduced epilogue. 128 points/block, 256 threads ---
template<bool PAD16>
__global__ __launch_bounds__(256) void k_mlp3(
    const unsigned short* __restrict__ k0b, const float* __restrict__ xyz,
    const int* __restrict__ rid, const unsigned short* __restrict__ vemb,
    const float* __restrict__ wts,
    const unsigned short* __restrict__ Wt0, const float* __restrict__ b0,
    const unsigned short* __restrict__ Wt1, const float* __restrict__ b1,
    const unsigned short* __restrict__ Wt2, const float* __restrict__ b2,
    float* __restrict__ out, int M) {

    __shared__ char featL[128 * 128];   // 64 bf16/row, XOR-swizzled
    __shared__ char hL[128 * 256];      // 128 bf16/row, XOR-swizzled
    __shared__ float diffL[128 * 3];
    __shared__ float wgtL[128];
    __shared__ int   ridL[128];

    const int t = threadIdx.x;
    const int base = blockIdx.x * 128;
    const int p = t >> 1;          // local point row
    const int dx = t & 1;          // this thread's x-corner
    const int i = base + p;

    float ch[12];
    #pragma unroll
    for (int c = 0; c < 12; c++) ch[c] = 0.f;
    float fz = 0.f, gz = 1.f;

    if (i < M) {
        int ix, iy, iz; float fx, fy;
        trisetup(xyz[3*i], xyz[3*i+1], xyz[3*i+2], ix, iy, iz, fx, fy, fz);
        gz = 1.f - fz;
        float wx = dx ? fx : (1.f - fx);
        float wy0 = wx * (1.f - fy), wy1 = wx * fy;
        #pragma unroll
        for (int dy = 0; dy < 2; dy++) {
            float w2 = dy ? wy1 : wy0;
            size_t vox = (size_t)((ix + dx) * 160 + (iy + dy)) * 160 + iz;
            unsigned int u0[6], u1[6];
            if (PAD16) {
                const char* pv = (const char*)k0b + vox * 32;
                u32x4 A = *(const u32x4*)(pv);
                u32x4 B = *(const u32x4*)(pv + 16);
                u32x4 C = *(const u32x4*)(pv + 32);
                u32x4 D = *(const u32x4*)(pv + 48);
                u0[0]=A[0]; u0[1]=A[1]; u0[2]=A[2]; u0[3]=A[3]; u0[4]=B[0]; u0[5]=B[1];
                u1[0]=C[0]; u1[1]=C[1]; u1[2]=C[2]; u1[3]=C[3]; u1[4]=D[0]; u1[5]=D[1];
            } else {
                const char* pv = (const char*)k0b + vox * 24;
                u32x2 a0 = *(const u32x2*)(pv);
                u32x2 a1 = *(const u32x2*)(pv + 8);
                u32x2 a2 = *(const u32x2*)(pv + 16);
                u32x2 a3 = *(const u32x2*)(pv + 24);
                u32x2 a4 = *(const u32x2*)(pv + 32);
                u32x2 a5 = *(const u32x2*)(pv + 40);
                u0[0]=a0[0]; u0[1]=a0[1]; u0[2]=a1[0]; u0[3]=a1[1]; u0[4]=a2[0]; u0[5]=a2[1];
                u1[0]=a3[0]; u1[1]=a3[1]; u1[2]=a4[0]; u1[3]=a4[1]; u1[4]=a5[0]; u1[5]=a5[1];
            }
            #pragma unroll
            for (int j = 0; j < 6; j++) {
                ch[2*j]   += w2 * (gz * blo(u0[j]) + fz * blo(u1[j]));
                ch[2*j+1] += w2 * (gz * bhi(u0[j]) + fz * bhi(u1[j]));
            }
        }
    }
    // combine the two x-corners of each point
    #pragma unroll
    for (int c = 0; c < 12; c++) ch[c] += __shfl_xor(ch[c], 1);

    if (dx == 0) {
        unsigned int fr[32];
        #pragma unroll
        for (int j = 0; j < 32; j++) fr[j] = 0u;
        float wpt = 0.f; int r = 0;
        if (i < M) {
            r = rid[i];
            wpt = wts[i];
            #pragma unroll
            for (int c = 0; c < 9; c++) {
                int k = c;
                fr[k >> 1] |= ((unsigned int)f2b(ch[3 + c])) << (16 * (k & 1));
            }
            const unsigned int* vp = (const unsigned int*)(vemb + (size_t)r * 28);
            unsigned int ve[14];
            #pragma unroll
            for (int j = 0; j < 14; j++) ve[j] = vp[j];
            #pragma unroll
            for (int j = 0; j < 27; j++) {
                unsigned int val = (ve[j >> 1] >> (16 * (j & 1))) & 0xffffu;
                int k = 9 + j;
                fr[k >> 1] |= val << (16 * (k & 1));
            }
        }
        diffL[p*3 + 0] = ch[0];
        diffL[p*3 + 1] = ch[1];
        diffL[p*3 + 2] = ch[2];
        wgtL[p] = wpt;
        ridL[p] = r;
        char* fp = featL + p * 128;
        unsigned int rs = (unsigned int)((p & 7) << 4);
        #pragma unroll
        for (int j = 0; j < 8; j++)
            *(u32x4*)(fp + ((16u*j) ^ rs)) = *(u32x4*)(fr + 4*j);
    }
    __syncthreads();

    const int lane = t & 63;
    const int w = t >> 6;
    const int g = lane >> 4;
    const int ln = lane & 15;

    // ---- layer 1: feat[128x64] @ Wt0 -> h[128x128] (relu, bf16) ----
    #pragma unroll
    for (int mi = 0; mi < 2; mi++) {
        const int m0 = 32*w + 16*mi;
        const int arow = m0 + ln;
        const unsigned int aswz = (unsigned int)((arow & 7) << 4);
        const char* ab = featL + arow * 128;
        short8 a0 = *(const short8*)(ab + ((16u*g)        ^ aswz));
        short8 a1 = *(const short8*)(ab + ((64u + 16u*g)  ^ aswz));
        #pragma unroll
        for (int nt = 0; nt < 8; nt++) {
            const int n0 = 16 * nt;
            float bias = b0[n0 + ln];
            f32x4 acc = {bias, bias, bias, bias};
            const char* wb = (const char*)Wt0 + (n0 + ln) * 128;
            acc = __builtin_amdgcn_mfma_f32_16x16x32_bf16(a0, *(const short8*)(wb + 16*g),      acc, 0, 0, 0);
            acc = __builtin_amdgcn_mfma_f32_16x16x32_bf16(a1, *(const short8*)(wb + 64 + 16*g), acc, 0, 0, 0);
            #pragma unroll
            for (int v = 0; v < 4; v++) {
                int row = m0 + 4*g + v;
                unsigned short hv = f2b(fmaxf(acc[v], 0.f));
                *(unsigned short*)(hL + (((unsigned)(row*256 + (n0+ln)*2)) ^ ((unsigned)((row & 7) << 4)))) = hv;
            }
        }
    }

    // ---- layer 2: h[128x128] @ Wt1 -> h2 (relu, bf16, in place: wave-private rows) ----
    #pragma unroll
    for (int mi = 0; mi < 2; mi++) {
        const int m0 = 32*w + 16*mi;
        const int arow = m0 + ln;
        const unsigned int aswz = (unsigned int)((arow & 7) << 4);
        const char* ab = hL + arow * 256;
        short8 a0 = *(const short8*)(ab + ((16u*g)         ^ aswz));
        short8 a1 = *(const short8*)(ab + ((64u  + 16u*g)  ^ aswz));
        short8 a2 = *(const short8*)(ab + ((128u + 16u*g)  ^ aswz));
        short8 a3 = *(const short8*)(ab + ((192u + 16u*g)  ^ aswz));
        #pragma unroll
        for (int nt = 0; nt < 8; nt++) {
            const int n0 = 16 * nt;
            float bias = b1[n0 + ln];
            f32x4 acc = {bias, bias, bias, bias};
            const char* wb = (const char*)Wt1 + (n0 + ln) * 256;
            acc = __builtin_amdgcn_mfma_f32_16x16x32_bf16(a0, *(const short8*)(wb + 16*g),       acc, 0, 0, 0);
            acc = __builtin_amdgcn_mfma_f32_16x16x32_bf16(a1, *(const short8*)(wb + 64 + 16*g),  acc, 0, 0, 0);
            acc = __builtin_amdgcn_mfma_f32_16x16x32_bf16(a2, *(const short8*)(wb + 128 + 16*g), acc, 0, 0, 0);
            acc = __builtin_amdgcn_mfma_f32_16x16x32_bf16(a3, *(const short8*)(wb + 192 + 16*g), acc, 0, 0, 0);
            #pragma unroll
            for (int v = 0; v < 4; v++) {
                int row = m0 + 4*g + v;
                unsigned short hv = f2b(fmaxf(acc[v], 0.f));
                *(unsigned short*)(hL + (((unsigned)(row*256 + (n0+ln)*2)) ^ ((unsigned)((row & 7) << 4)))) = hv;
            }
        }
    }

    // ---- layer 3 + sigmoid + per-ray-reduced atomics ----
    const float b2c = (ln < 3) ? b2[ln] : 0.f;
    #pragma unroll
    for (int mi = 0; mi < 2; mi++) {
        const int m0 = 32*w + 16*mi;
        const int arow = m0 + ln;
        const unsigned int aswz = (unsigned int)((arow & 7) << 4);
        const char* ab = hL + arow * 256;
        short8 a0 = *(const short8*)(ab + ((16u*g)         ^ aswz));
        short8 a1 = *(const short8*)(ab + ((64u  + 16u*g)  ^ aswz));
        short8 a2 = *(const short8*)(ab + ((128u + 16u*g)  ^ aswz));
        short8 a3 = *(const short8*)(ab + ((192u + 16u*g)  ^ aswz));
        f32x4 acc = {0.f, 0.f, 0.f, 0.f};
        const char* wb = (const char*)Wt2 + ln * 256;
        acc = __builtin_amdgcn_mfma_f32_16x16x32_bf16(a0, *(const short8*)(wb + 16*g),       acc, 0, 0, 0);
        acc = __builtin_amdgcn_mfma_f32_16x16x32_bf16(a1, *(const short8*)(wb + 64 + 16*g),  acc, 0, 0, 0);
        acc = __builtin_amdgcn_mfma_f32_16x16x32_bf16(a2, *(const short8*)(wb + 128 + 16*g), acc, 0, 0, 0);
        acc = __builtin_amdgcn_mfma_f32_16x16x32_bf16(a3, *(const short8*)(wb + 192 + 16*g), acc, 0, 0, 0);

        float val[4];
        #pragma unroll
        for (int v = 0; v < 4; v++) {
            int row = m0 + 4*g + v;
            float logit = acc[v] + b2c + diffL[row*3 + ln];
            val[v] = (ln < 3) ? wgtL[row] / (1.f + expf(-logit)) : 0.f;
        }
        int r0t = ridL[m0], r15t = ridL[m0 + 15];
        if (r0t == r15t) {
            float s = val[0] + val[1] + val[2] + val[3];
            s += __shfl_xor(s, 16);
            s += __shfl_xor(s, 32);
            if (g == 0 && ln < 3) atomicAdd(out + 3*r0t + ln, s);
        } else if (ln < 3) {
            int rr = ridL[m0 + 4*g];
            float run = val[0];
            #pragma unroll
            for (int v = 1; v < 4; v++) {
                int rv = ridL[m0 + 4*g + v];
                if (rv == rr) run += val[v];
                else { atomicAdd(out + 3*rr + ln, run); run = val[v]; rr = rv; }
            }
            atomicAdd(out + 3*rr + ln, run);
        }
    }
}

extern "C" void kernel_launch(void* const* d_in, const int* in_sizes, int n_in,
                              void* d_out, int out_size, void* d_ws, size_t ws_size,
                              hipStream_t stream) {
    const float* dg  = (const float*)d_in[0];
    const float* k0  = (const float*)d_in[1];
    const float* xyz = (const float*)d_in[2];
    const float* vd  = (const float*)d_in[3];
    const float* W0  = (const float*)d_in[4];
    const float* b0  = (const float*)d_in[5];
    const float* W1  = (const float*)d_in[6];
    const float* b1  = (const float*)d_in[7];
    const float* W2  = (const float*)d_in[8];
    const float* b2  = (const float*)d_in[9];
    const int*   rid = (const int*)d_in[10];
    float* out = (float*)d_out;

    const int M = in_sizes[2] / 3;
    const int R = in_sizes[3] / 3;

    const size_t tail = (size_t)(128*64 + 128*128 + 16*128) * 2 + (size_t)R * 28 * 2
                      + (size_t)M * 12 + (size_t)(R + 1) * 4 + 4096;
    const bool pad16 = (ws_size >= (size_t)NVOX * 32 + tail);
    const size_t voxb = pad16 ? 32 : 24;

    char* w = (char*)d_ws;
    unsigned short* k0b  = (unsigned short*)w;  w += (size_t)NVOX * voxb;
    unsigned short* Wt0  = (unsigned short*)w;  w += 128 * 64 * 2;
    unsigned short* Wt1  = (unsigned short*)w;  w += 128 * 128 * 2;
    unsigned short* Wt2  = (unsigned short*)w;  w += 16 * 128 * 2;
    unsigned short* vembb= (unsigned short*)w;  w += (size_t)R * 28 * 2;
    float* alpha   = (float*)w;  w += (size_t)M * 4;
    float* log1ma  = (float*)w;  w += (size_t)M * 4;
    float* wts     = (float*)w;  w += (size_t)M * 4;
    int*   starts  = (int*)w;    w += (size_t)(R + 1) * 4;

    if (pad16) k_t<true> <<<dim3((NVOX + 255) / 256), dim3(256), 0, stream>>>(k0, k0b);
    else       k_t<false><<<dim3((NVOX + 255) / 256), dim3(256), 0, stream>>>(k0, k0b);
    k_wprep  <<<dim3(64), dim3(256), 0, stream>>>(W0, W1, W2, Wt0, Wt1, Wt2);
    k_density<<<dim3((M + 255) / 256), dim3(256), 0, stream>>>(dg, xyz, alpha, log1ma, M);
    k_starts <<<dim3((R + 1 + 255) / 256), dim3(256), 0, stream>>>(rid, starts, M, R);
    k_vdemb  <<<dim3((R + 255) / 256), dim3(256), 0, stream>>>(vd, vembb, R);
    k_scan   <<<dim3((R + 255) / 256), dim3(256), 0, stream>>>(alpha, log1ma, starts, wts, out, R);
    if (pad16)
        k_mlp3<true> <<<dim3((M + 127) / 128), dim3(256), 0, stream>>>(k0b, xyz, rid, vembb, wts,
                                                                       Wt0, b0, Wt1, b1, Wt2, b2, out, M);
    else
        k_mlp3<false><<<dim3((M + 127) / 128), dim3(256), 0, stream>>>(k0b, xyz, rid, vembb, wts,
                                                                       Wt0, b0, Wt1, b1, Wt2, b2, out, M);
}

// Round 4
// 858.687 us; speedup vs baseline: 4.0753x; 1.1418x over previous
//
#include <hip/hip_runtime.h>

#define ACT_SHIFT (-4.5951198501345898f)   // log(1/(1-0.01) - 1)
#define DELTA 0.5f
#define XS 25600                            // 160*160
#define YS 160
#define NVOX 4096000

typedef __attribute__((ext_vector_type(8))) short short8;
typedef __attribute__((ext_vector_type(4))) float f32x4;
typedef __attribute__((ext_vector_type(2))) unsigned int u32x2;
typedef __attribute__((ext_vector_type(4))) unsigned int u32x4;

__device__ __forceinline__ float softplusf(float x) {
    return x > 20.f ? x : log1pf(expf(x));
}
__device__ __forceinline__ unsigned short f2b(float x) {
    unsigned int u = __float_as_uint(x);
    u += 0x7fffu + ((u >> 16) & 1u);
    return (unsigned short)(u >> 16);
}
__device__ __forceinline__ float blo(unsigned int u) { return __uint_as_float(u << 16); }
__device__ __forceinline__ float bhi(unsigned int u) { return __uint_as_float(u & 0xffff0000u); }

__device__ __forceinline__ void trisetup(float px, float py, float pz,
                                         int& ix, int& iy, int& iz,
                                         float& fx, float& fy, float& fz) {
    float sx = (px + 1.f) * 0.5f * 159.f;
    float sy = (py + 1.f) * 0.5f * 159.f;
    float sz = (pz + 1.f) * 0.5f * 159.f;
    sx = fminf(fmaxf(sx, 0.f), 159.f);
    sy = fminf(fmaxf(sy, 0.f), 159.f);
    sz = fminf(fmaxf(sz, 0.f), 159.f);
    ix = (int)sx; if (ix > 158) ix = 158;
    iy = (int)sy; if (iy > 158) iy = 158;
    iz = (int)sz; if (iz > 158) iz = 158;
    fx = sx - (float)ix;
    fy = sy - (float)iy;
    fz = sz - (float)iz;
}

// ================= grid builders =================
// VOX64: entry(x,y,z) = {ch0..11(z) bf16, ch0..11(z+1) bf16, d(z) f32, d(z+1) f32, pad}
__global__ void k_t64(const float* __restrict__ k0, const float* __restrict__ dg,
                      unsigned int* __restrict__ grid) {
    int tid = blockIdx.x * 256 + threadIdx.x;
    if (tid >= NVOX) return;
    int z = tid % 160;
    int t1 = (z < 159) ? tid + 1 : tid;
    unsigned int w[16];
    #pragma unroll
    for (int j = 0; j < 6; j++) {
        w[j]   = (unsigned int)f2b(k0[(size_t)(2*j)*NVOX + tid]) | ((unsigned int)f2b(k0[(size_t)(2*j+1)*NVOX + tid]) << 16);
        w[6+j] = (unsigned int)f2b(k0[(size_t)(2*j)*NVOX + t1])  | ((unsigned int)f2b(k0[(size_t)(2*j+1)*NVOX + t1])  << 16);
    }
    w[12] = __float_as_uint(dg[tid]);
    w[13] = __float_as_uint(dg[t1]);
    w[14] = 0u; w[15] = 0u;
    u32x4* dst = (u32x4*)(grid + (size_t)tid * 16);
    dst[0] = *(u32x4*)(w);  dst[1] = *(u32x4*)(w+4);
    dst[2] = *(u32x4*)(w+8); dst[3] = *(u32x4*)(w+12);
}

// VOX32: entry(x,y,z) = {ch0..11(z) bf16 (24B), d(z) f32, pad}
__global__ void k_t32(const float* __restrict__ k0, const float* __restrict__ dg,
                      unsigned int* __restrict__ grid) {
    int tid = blockIdx.x * 256 + threadIdx.x;
    if (tid >= NVOX) return;
    unsigned int w[8];
    #pragma unroll
    for (int j = 0; j < 6; j++)
        w[j] = (unsigned int)f2b(k0[(size_t)(2*j)*NVOX + tid]) | ((unsigned int)f2b(k0[(size_t)(2*j+1)*NVOX + tid]) << 16);
    w[6] = __float_as_uint(dg[tid]);
    w[7] = 0u;
    u32x4* dst = (u32x4*)(grid + (size_t)tid * 8);
    dst[0] = *(u32x4*)(w); dst[1] = *(u32x4*)(w+4);
}

// VOX24: entry(x,y,z) = {ch0..11(z) bf16} (no density)
__global__ void k_t24(const float* __restrict__ k0, unsigned int* __restrict__ grid) {
    int tid = blockIdx.x * 256 + threadIdx.x;
    if (tid >= NVOX) return;
    unsigned int o[6];
    #pragma unroll
    for (int j = 0; j < 6; j++)
        o[j] = (unsigned int)f2b(k0[(size_t)(2*j)*NVOX + tid]) | ((unsigned int)f2b(k0[(size_t)(2*j+1)*NVOX + tid]) << 16);
    unsigned int* dst = grid + (size_t)tid * 6;
    #pragma unroll
    for (int j = 0; j < 6; j++) dst[j] = o[j];
}

// ================= small prep kernels =================
__global__ void k_wprep(const float* __restrict__ W0, const float* __restrict__ W1,
                        const float* __restrict__ W2,
                        unsigned short* __restrict__ Wt0, unsigned short* __restrict__ Wt1,
                        unsigned short* __restrict__ Wt2) {
    int id = blockIdx.x * 256 + threadIdx.x;
    if (id < 128 * 64)  { int n = id >> 6, k = id & 63;  Wt0[id] = (k < 36) ? f2b(W0[k*128 + n]) : 0; }
    if (id < 128 * 128) { int n = id >> 7, k = id & 127; Wt1[id] = f2b(W1[k*128 + n]); }
    if (id < 16 * 128)  { int n = id >> 7, k = id & 127; Wt2[id] = (n < 3) ? f2b(W2[k*3 + n]) : 0; }
}

__global__ void k_starts(const int* __restrict__ rid, int* __restrict__ starts, int M, int R) {
    int r = blockIdx.x * blockDim.x + threadIdx.x;
    if (r > R) return;
    int lo = 0, hi = M;
    while (lo < hi) { int mid = (lo + hi) >> 1; if (rid[mid] < r) lo = mid + 1; else hi = mid; }
    starts[r] = lo;
}

__global__ void k_vdemb(const float* __restrict__ vd, unsigned short* __restrict__ emb, int R) {
    int r = blockIdx.x * blockDim.x + threadIdx.x;
    if (r >= R) return;
    float e[28];
    float v0 = vd[3*r], v1 = vd[3*r+1], v2 = vd[3*r+2];
    e[0] = v0; e[1] = v1; e[2] = v2;
    float v[3] = {v0, v1, v2};
    #pragma unroll
    for (int d = 0; d < 3; d++) {
        #pragma unroll
        for (int p = 0; p < 4; p++) {
            float a = v[d] * (float)(1 << p);
            e[3 + d*4 + p]  = sinf(a);
            e[15 + d*4 + p] = cosf(a);
        }
    }
    e[27] = 0.f;
    unsigned short* o = emb + r * 28;
    #pragma unroll
    for (int j = 0; j < 28; j++) o[j] = f2b(e[j]);
}

// legacy density pass (VOX24 fused fallback); writes packed {alpha, log1ma}
__global__ void k_densityC(const float* __restrict__ dg, const float* __restrict__ xyz,
                           float2* __restrict__ alog, int M) {
    int i = blockIdx.x * blockDim.x + threadIdx.x;
    if (i >= M) return;
    int ix, iy, iz; float fx, fy, fz;
    trisetup(xyz[3*i], xyz[3*i+1], xyz[3*i+2], ix, iy, iz, fx, fy, fz);
    const float* g = dg + ix * XS + iy * YS + iz;
    float gx = 1.f - fx, gy = 1.f - fy, gz = 1.f - fz;
    float v =
        gx * (gy * (gz * g[0]      + fz * g[1])      + fy * (gz * g[YS]      + fz * g[YS+1])) +
        fx * (gy * (gz * g[XS]     + fz * g[XS+1])   + fy * (gz * g[XS+YS]   + fz * g[XS+YS+1]));
    float sp = softplusf(v + ACT_SHIFT);
    float l  = -sp * DELTA;
    alog[i] = make_float2(1.f - expf(l), fmaxf(l, -15.9424285f));
}

// ================= gather (split pipeline): 2 threads/point =================
// rec[i] (32B): w0=c3|c4 w1=c5|c6 w2=c7|c8 w3=c9|c10 w4=c11|0 w5..7=diff f32
template<int VOX>
__global__ __launch_bounds__(256) void k_gather(
    const unsigned int* __restrict__ grid, const float* __restrict__ dg,
    const float* __restrict__ xyz,
    u32x4* __restrict__ rec, float2* __restrict__ alog, int M) {

    const int t = blockIdx.x * 256 + threadIdx.x;
    const int p = t >> 1;
    const int dx = t & 1;
    if (p >= M) return;
    const int i = p;

    int ix, iy, iz; float fx, fy, fz;
    trisetup(xyz[3*i], xyz[3*i+1], xyz[3*i+2], ix, iy, iz, fx, fy, fz);
    float gz = 1.f - fz;
    float wx = dx ? fx : (1.f - fx);
    float wy[2] = {wx * (1.f - fy), wx * fy};

    float ch[12];
    #pragma unroll
    for (int c = 0; c < 12; c++) ch[c] = 0.f;
    float dd = 0.f;
    const int x = ix + dx;

    #pragma unroll
    for (int dy = 0; dy < 2; dy++) {
        float wc = wy[dy];
        size_t idx = (size_t)(x * 160 + (iy + dy)) * 160 + iz;
        if (VOX == 64) {
            const u32x4* e = (const u32x4*)(grid + idx * 16);
            u32x4 q0 = e[0], q1 = e[1], q2 = e[2], q3 = e[3];
            unsigned int wz[6]  = {q0[0],q0[1],q0[2],q0[3],q1[0],q1[1]};
            unsigned int wz1[6] = {q1[2],q1[3],q2[0],q2[1],q2[2],q2[3]};
            #pragma unroll
            for (int j = 0; j < 6; j++) {
                ch[2*j]   += wc * (gz * blo(wz[j]) + fz * blo(wz1[j]));
                ch[2*j+1] += wc * (gz * bhi(wz[j]) + fz * bhi(wz1[j]));
            }
            dd += wc * (gz * __uint_as_float(q3[0]) + fz * __uint_as_float(q3[1]));
        } else if (VOX == 32) {
            const u32x4* e0 = (const u32x4*)(grid + idx * 8);
            const u32x4* e1 = (const u32x4*)(grid + (idx + 1) * 8);
            u32x4 a0 = e0[0], a1 = e0[1], b0 = e1[0], b1 = e1[1];
            unsigned int wz[6]  = {a0[0],a0[1],a0[2],a0[3],a1[0],a1[1]};
            unsigned int wz1[6] = {b0[0],b0[1],b0[2],b0[3],b1[0],b1[1]};
            #pragma unroll
            for (int j = 0; j < 6; j++) {
                ch[2*j]   += wc * (gz * blo(wz[j]) + fz * blo(wz1[j]));
                ch[2*j+1] += wc * (gz * bhi(wz[j]) + fz * bhi(wz1[j]));
            }
            dd += wc * (gz * __uint_as_float(a1[2]) + fz * __uint_as_float(b1[2]));
        } else {
            const u32x2* e = (const u32x2*)(grid + idx * 6);
            u32x2 a0 = e[0], a1 = e[1], a2 = e[2], a3 = e[3], a4 = e[4], a5 = e[5];
            unsigned int wz[6]  = {a0[0],a0[1],a1[0],a1[1],a2[0],a2[1]};
            unsigned int wz1[6] = {a3[0],a3[1],a4[0],a4[1],a5[0],a5[1]};
            #pragma unroll
            for (int j = 0; j < 6; j++) {
                ch[2*j]   += wc * (gz * blo(wz[j]) + fz * blo(wz1[j]));
                ch[2*j+1] += wc * (gz * bhi(wz[j]) + fz * bhi(wz1[j]));
            }
            const float* dr = dg + (size_t)(x * 160 + (iy + dy)) * 160 + iz;
            dd += wc * (gz * dr[0] + fz * dr[1]);
        }
    }

    #pragma unroll
    for (int c = 0; c < 12; c++) ch[c] += __shfl_xor(ch[c], 1);
    dd += __shfl_xor(dd, 1);

    if (dx == 0) {
        unsigned int w[8];
        w[0] = (unsigned int)f2b(ch[3]) | ((unsigned int)f2b(ch[4]) << 16);
        w[1] = (unsigned int)f2b(ch[5]) | ((unsigned int)f2b(ch[6]) << 16);
        w[2] = (unsigned int)f2b(ch[7]) | ((unsigned int)f2b(ch[8]) << 16);
        w[3] = (unsigned int)f2b(ch[9]) | ((unsigned int)f2b(ch[10]) << 16);
        w[4] = (unsigned int)f2b(ch[11]);
        w[5] = __float_as_uint(ch[0]);
        w[6] = __float_as_uint(ch[1]);
        w[7] = __float_as_uint(ch[2]);
        rec[(size_t)i*2]     = *(u32x4*)(w);
        rec[(size_t)i*2 + 1] = *(u32x4*)(w + 4);
    } else {
        float sp = softplusf(dd + ACT_SHIFT);
        float l  = -sp * DELTA;
        alog[i] = make_float2(1.f - expf(l), fmaxf(l, -15.9424285f));
    }
}

// ================= wave-per-ray scan =================
__global__ void k_scanw(const float2* __restrict__ alog, const int* __restrict__ starts,
                        float* __restrict__ wts, float* __restrict__ out, int R) {
    const int r = (blockIdx.x * blockDim.x + threadIdx.x) >> 6;
    const int lane = threadIdx.x & 63;
    if (r >= R) return;
    const int s = starts[r], e = starts[r + 1];
    float carry = 0.f;
    for (int i0 = s; i0 < e; i0 += 64) {
        int idx = i0 + lane;
        bool pr = idx < e;
        float a = 0.f, x = 0.f;
        if (pr) { float2 v = alog[idx]; a = v.x; x = v.y; }
        float incl = x;
        #pragma unroll
        for (int d = 1; d < 64; d <<= 1) {
            float tv = __shfl_up(incl, d);
            if (lane >= d) incl += tv;
        }
        if (pr) wts[idx] = a * expf(carry + (incl - x));
        carry += __shfl(incl, 63);
    }
    float ainv = expf(carry);
    if (lane == 0) { out[3*r] = ainv; out[3*r+1] = ainv; out[3*r+2] = ainv; }
}

// ================= MFMA MLP (split pipeline) =================
__global__ __launch_bounds__(256) void k_mlp_s(
    const u32x4* __restrict__ rec, const int* __restrict__ rid,
    const unsigned short* __restrict__ vemb, const float* __restrict__ wts,
    const unsigned short* __restrict__ Wt0, const float* __restrict__ b0,
    const unsigned short* __restrict__ Wt1, const float* __restrict__ b1,
    const unsigned short* __restrict__ Wt2, const float* __restrict__ b2,
    float* __restrict__ out, int M) {

    __shared__ char featL[128 * 128];
    __shared__ char hL[128 * 256];
    __shared__ float diffL[128 * 3];
    __shared__ float wgtL[128];
    __shared__ int   ridL[128];

    const int t = threadIdx.x;
    const int base = blockIdx.x * 128;

    if (t < 128) {
        const int i = base + t;
        unsigned int fr[32];
        #pragma unroll
        for (int j = 0; j < 32; j++) fr[j] = 0u;
        float wpt = 0.f; int r = 0;
        float d0 = 0.f, d1 = 0.f, d2 = 0.f;
        if (i < M) {
            u32x4 r0 = rec[(size_t)i*2];
            u32x4 r1 = rec[(size_t)i*2 + 1];
            fr[0] = r0[0]; fr[1] = r0[1]; fr[2] = r0[2]; fr[3] = r0[3];
            fr[4] = r1[0] & 0xffffu;
            d0 = __uint_as_float(r1[1]); d1 = __uint_as_float(r1[2]); d2 = __uint_as_float(r1[3]);
            r = rid[i];
            wpt = wts[i];
            const unsigned int* vp = (const unsigned int*)(vemb + (size_t)r * 28);
            unsigned int ve[14];
            #pragma unroll
            for (int j = 0; j < 14; j++) ve[j] = vp[j];
            #pragma unroll
            for (int j = 0; j < 27; j++) {
                unsigned int val = (ve[j >> 1] >> (16 * (j & 1))) & 0xffffu;
                int k = 9 + j;
                fr[k >> 1] |= val << (16 * (k & 1));
            }
        }
        diffL[t*3 + 0] = d0; diffL[t*3 + 1] = d1; diffL[t*3 + 2] = d2;
        wgtL[t] = wpt;
        ridL[t] = r;
        char* fp = featL + t * 128;
        unsigned int rs = (unsigned int)((t & 7) << 4);
        #pragma unroll
        for (int j = 0; j < 8; j++)
            *(u32x4*)(fp + ((16u*j) ^ rs)) = *(u32x4*)(fr + 4*j);
    }
    __syncthreads();

    const int lane = t & 63;
    const int w = t >> 6;
    const int g = lane >> 4;
    const int ln = lane & 15;

    // ---- layer 1 ----
    #pragma unroll
    for (int mi = 0; mi < 2; mi++) {
        const int m0 = 32*w + 16*mi;
        const int arow = m0 + ln;
        const unsigned int aswz = (unsigned int)((arow & 7) << 4);
        const char* ab = featL + arow * 128;
        short8 a0 = *(const short8*)(ab + ((16u*g)        ^ aswz));
        short8 a1 = *(const short8*)(ab + ((64u + 16u*g)  ^ aswz));
        #pragma unroll
        for (int nt = 0; nt < 8; nt++) {
            const int n0 = 16 * nt;
            float bias = b0[n0 + ln];
            f32x4 acc = {bias, bias, bias, bias};
            const char* wb = (const char*)Wt0 + (n0 + ln) * 128;
            acc = __builtin_amdgcn_mfma_f32_16x16x32_bf16(a0, *(const short8*)(wb + 16*g),      acc, 0, 0, 0);
            acc = __builtin_amdgcn_mfma_f32_16x16x32_bf16(a1, *(const short8*)(wb + 64 + 16*g), acc, 0, 0, 0);
            #pragma unroll
            for (int v = 0; v < 4; v++) {
                int row = m0 + 4*g + v;
                unsigned short hv = f2b(fmaxf(acc[v], 0.f));
                *(unsigned short*)(hL + (((unsigned)(row*256 + (n0+ln)*2)) ^ ((unsigned)((row & 7) << 4)))) = hv;
            }
        }
    }

    // ---- layer 2 (in place; wave-private rows) ----
    #pragma unroll
    for (int mi = 0; mi < 2; mi++) {
        const int m0 = 32*w + 16*mi;
        const int arow = m0 + ln;
        const unsigned int aswz = (unsigned int)((arow & 7) << 4);
        const char* ab = hL + arow * 256;
        short8 a0 = *(const short8*)(ab + ((16u*g)         ^ aswz));
        short8 a1 = *(const short8*)(ab + ((64u  + 16u*g)  ^ aswz));
        short8 a2 = *(const short8*)(ab + ((128u + 16u*g)  ^ aswz));
        short8 a3 = *(const short8*)(ab + ((192u + 16u*g)  ^ aswz));
        #pragma unroll
        for (int nt = 0; nt < 8; nt++) {
            const int n0 = 16 * nt;
            float bias = b1[n0 + ln];
            f32x4 acc = {bias, bias, bias, bias};
            const char* wb = (const char*)Wt1 + (n0 + ln) * 256;
            acc = __builtin_amdgcn_mfma_f32_16x16x32_bf16(a0, *(const short8*)(wb + 16*g),       acc, 0, 0, 0);
            acc = __builtin_amdgcn_mfma_f32_16x16x32_bf16(a1, *(const short8*)(wb + 64 + 16*g),  acc, 0, 0, 0);
            acc = __builtin_amdgcn_mfma_f32_16x16x32_bf16(a2, *(const short8*)(wb + 128 + 16*g), acc, 0, 0, 0);
            acc = __builtin_amdgcn_mfma_f32_16x16x32_bf16(a3, *(const short8*)(wb + 192 + 16*g), acc, 0, 0, 0);
            #pragma unroll
            for (int v = 0; v < 4; v++) {
                int row = m0 + 4*g + v;
                unsigned short hv = f2b(fmaxf(acc[v], 0.f));
                *(unsigned short*)(hL + (((unsigned)(row*256 + (n0+ln)*2)) ^ ((unsigned)((row & 7) << 4)))) = hv;
            }
        }
    }

    // ---- layer 3 + sigmoid + ray-merged atomics ----
    const float b2c = (ln < 3) ? b2[ln] : 0.f;
    #pragma unroll
    for (int mi = 0; mi < 2; mi++) {
        const int m0 = 32*w + 16*mi;
        const int arow = m0 + ln;
        const unsigned int aswz = (unsigned int)((arow & 7) << 4);
        const char* ab = hL + arow * 256;
        short8 a0 = *(const short8*)(ab + ((16u*g)         ^ aswz));
        short8 a1 = *(const short8*)(ab + ((64u  + 16u*g)  ^ aswz));
        short8 a2 = *(const short8*)(ab + ((128u + 16u*g)  ^ aswz));
        short8 a3 = *(const short8*)(ab + ((192u + 16u*g)  ^ aswz));
        f32x4 acc = {0.f, 0.f, 0.f, 0.f};
        const char* wb = (const char*)Wt2 + ln * 256;
        acc = __builtin_amdgcn_mfma_f32_16x16x32_bf16(a0, *(const short8*)(wb + 16*g),       acc, 0, 0, 0);
        acc = __builtin_amdgcn_mfma_f32_16x16x32_bf16(a1, *(const short8*)(wb + 64 + 16*g),  acc, 0, 0, 0);
        acc = __builtin_amdgcn_mfma_f32_16x16x32_bf16(a2, *(const short8*)(wb + 128 + 16*g), acc, 0, 0, 0);
        acc = __builtin_amdgcn_mfma_f32_16x16x32_bf16(a3, *(const short8*)(wb + 192 + 16*g), acc, 0, 0, 0);

        float val[4];
        #pragma unroll
        for (int v = 0; v < 4; v++) {
            int row = m0 + 4*g + v;
            float logit = acc[v] + b2c + diffL[row*3 + ln];
            val[v] = (ln < 3) ? wgtL[row] / (1.f + expf(-logit)) : 0.f;
        }
        int r0t = ridL[m0], r15t = ridL[m0 + 15];
        if (r0t == r15t) {
            float s = val[0] + val[1] + val[2] + val[3];
            s += __shfl_xor(s, 16);
            s += __shfl_xor(s, 32);
            if (g == 0 && ln < 3) atomicAdd(out + 3*r0t + ln, s);
        } else if (ln < 3) {
            int rr = ridL[m0 + 4*g];
            float run = val[0];
            #pragma unroll
            for (int v = 1; v < 4; v++) {
                int rv = ridL[m0 + 4*g + v];
                if (rv == rr) run += val[v];
                else { atomicAdd(out + 3*rr + ln, run); run = val[v]; rr = rv; }
            }
            atomicAdd(out + 3*rr + ln, run);
        }
    }
}

// ================= legacy fused MLP (ultra fallback, 24B grid) =================
__global__ __launch_bounds__(256) void k_mlp_fused(
    const unsigned short* __restrict__ k0b, const float* __restrict__ xyz,
    const int* __restrict__ rid, const unsigned short* __restrict__ vemb,
    const float* __restrict__ wts,
    const unsigned short* __restrict__ Wt0, const float* __restrict__ b0,
    const unsigned short* __restrict__ Wt1, const float* __restrict__ b1,
    const unsigned short* __restrict__ Wt2, const float* __restrict__ b2,
    float* __restrict__ out, int M) {

    __shared__ char featL[128 * 128];
    __shared__ char hL[128 * 256];
    __shared__ float diffL[128 * 3];
    __shared__ float wgtL[128];
    __shared__ int   ridL[128];

    const int t = threadIdx.x;
    const int base = blockIdx.x * 128;
    const int p = t >> 1;
    const int dx = t & 1;
    const int i = base + p;

    float ch[12];
    #pragma unroll
    for (int c = 0; c < 12; c++) ch[c] = 0.f;

    if (i < M) {
        int ix, iy, iz; float fx, fy, fz;
        trisetup(xyz[3*i], xyz[3*i+1], xyz[3*i+2], ix, iy, iz, fx, fy, fz);
        float gz = 1.f - fz;
        float wx = dx ? fx : (1.f - fx);
        float wy0 = wx * (1.f - fy), wy1 = wx * fy;
        #pragma unroll
        for (int dy = 0; dy < 2; dy++) {
            float w2 = dy ? wy1 : wy0;
            size_t vox = (size_t)((ix + dx) * 160 + (iy + dy)) * 160 + iz;
            const char* pv = (const char*)k0b + vox * 24;
            u32x2 a0 = *(const u32x2*)(pv);
            u32x2 a1 = *(const u32x2*)(pv + 8);
            u32x2 a2 = *(const u32x2*)(pv + 16);
            u32x2 a3 = *(const u32x2*)(pv + 24);
            u32x2 a4 = *(const u32x2*)(pv + 32);
            u32x2 a5 = *(const u32x2*)(pv + 40);
            unsigned int u0[6] = {a0[0],a0[1],a1[0],a1[1],a2[0],a2[1]};
            unsigned int u1[6] = {a3[0],a3[1],a4[0],a4[1],a5[0],a5[1]};
            #pragma unroll
            for (int j = 0; j < 6; j++) {
                ch[2*j]   += w2 * (gz * blo(u0[j]) + fz * blo(u1[j]));
                ch[2*j+1] += w2 * (gz * bhi(u0[j]) + fz * bhi(u1[j]));
            }
        }
    }
    #pragma unroll
    for (int c = 0; c < 12; c++) ch[c] += __shfl_xor(ch[c], 1);

    if (dx == 0) {
        unsigned int fr[32];
        #pragma unroll
        for (int j = 0; j < 32; j++) fr[j] = 0u;
        float wpt = 0.f; int r = 0;
        if (i < M) {
            r = rid[i];
            wpt = wts[i];
            #pragma unroll
            for (int c = 0; c < 9; c++) {
                int k = c;
                fr[k >> 1] |= ((unsigned int)f2b(ch[3 + c])) << (16 * (k & 1));
            }
            const unsigned int* vp = (const unsigned int*)(vemb + (size_t)r * 28);
            unsigned int ve[14];
            #pragma unroll
            for (int j = 0; j < 14; j++) ve[j] = vp[j];
            #pragma unroll
            for (int j = 0; j < 27; j++) {
                unsigned int val = (ve[j >> 1] >> (16 * (j & 1))) & 0xffffu;
                int k = 9 + j;
                fr[k >> 1] |= val << (16 * (k & 1));
            }
        }
        diffL[p*3 + 0] = ch[0];
        diffL[p*3 + 1] = ch[1];
        diffL[p*3 + 2] = ch[2];
        wgtL[p] = wpt;
        ridL[p] = r;
        char* fp = featL + p * 128;
        unsigned int rs = (unsigned int)((p & 7) << 4);
        #pragma unroll
        for (int j = 0; j < 8; j++)
            *(u32x4*)(fp + ((16u*j) ^ rs)) = *(u32x4*)(fr + 4*j);
    }
    __syncthreads();

    const int lane = t & 63;
    const int w = t >> 6;
    const int g = lane >> 4;
    const int ln = lane & 15;

    #pragma unroll
    for (int mi = 0; mi < 2; mi++) {
        const int m0 = 32*w + 16*mi;
        const int arow = m0 + ln;
        const unsigned int aswz = (unsigned int)((arow & 7) << 4);
        const char* ab = featL + arow * 128;
        short8 a0 = *(const short8*)(ab + ((16u*g)        ^ aswz));
        short8 a1 = *(const short8*)(ab + ((64u + 16u*g)  ^ aswz));
        #pragma unroll
        for (int nt = 0; nt < 8; nt++) {
            const int n0 = 16 * nt;
            float bias = b0[n0 + ln];
            f32x4 acc = {bias, bias, bias, bias};
            const char* wb = (const char*)Wt0 + (n0 + ln) * 128;
            acc = __builtin_amdgcn_mfma_f32_16x16x32_bf16(a0, *(const short8*)(wb + 16*g),      acc, 0, 0, 0);
            acc = __builtin_amdgcn_mfma_f32_16x16x32_bf16(a1, *(const short8*)(wb + 64 + 16*g), acc, 0, 0, 0);
            #pragma unroll
            for (int v = 0; v < 4; v++) {
                int row = m0 + 4*g + v;
                unsigned short hv = f2b(fmaxf(acc[v], 0.f));
                *(unsigned short*)(hL + (((unsigned)(row*256 + (n0+ln)*2)) ^ ((unsigned)((row & 7) << 4)))) = hv;
            }
        }
    }

    #pragma unroll
    for (int mi = 0; mi < 2; mi++) {
        const int m0 = 32*w + 16*mi;
        const int arow = m0 + ln;
        const unsigned int aswz = (unsigned int)((arow & 7) << 4);
        const char* ab = hL + arow * 256;
        short8 a0 = *(const short8*)(ab + ((16u*g)         ^ aswz));
        short8 a1 = *(const short8*)(ab + ((64u  + 16u*g)  ^ aswz));
        short8 a2 = *(const short8*)(ab + ((128u + 16u*g)  ^ aswz));
        short8 a3 = *(const short8*)(ab + ((192u + 16u*g)  ^ aswz));
        #pragma unroll
        for (int nt = 0; nt < 8; nt++) {
            const int n0 = 16 * nt;
            float bias = b1[n0 + ln];
            f32x4 acc = {bias, bias, bias, bias};
            const char* wb = (const char*)Wt1 + (n0 + ln) * 256;
            acc = __builtin_amdgcn_mfma_f32_16x16x32_bf16(a0, *(const short8*)(wb + 16*g),       acc, 0, 0, 0);
            acc = __builtin_amdgcn_mfma_f32_16x16x32_bf16(a1, *(const short8*)(wb + 64 + 16*g),  acc, 0, 0, 0);
            acc = __builtin_amdgcn_mfma_f32_16x16x32_bf16(a2, *(const short8*)(wb + 128 + 16*g), acc, 0, 0, 0);
            acc = __builtin_amdgcn_mfma_f32_16x16x32_bf16(a3, *(const short8*)(wb + 192 + 16*g), acc, 0, 0, 0);
            #pragma unroll
            for (int v = 0; v < 4; v++) {
                int row = m0 + 4*g + v;
                unsigned short hv = f2b(fmaxf(acc[v], 0.f));
                *(unsigned short*)(hL + (((unsigned)(row*256 + (n0+ln)*2)) ^ ((unsigned)((row & 7) << 4)))) = hv;
            }
        }
    }

    const float b2c = (ln < 3) ? b2[ln] : 0.f;
    #pragma unroll
    for (int mi = 0; mi < 2; mi++) {
        const int m0 = 32*w + 16*mi;
        const int arow = m0 + ln;
        const unsigned int aswz = (unsigned int)((arow & 7) << 4);
        const char* ab = hL + arow * 256;
        short8 a0 = *(const short8*)(ab + ((16u*g)         ^ aswz));
        short8 a1 = *(const short8*)(ab + ((64u  + 16u*g)  ^ aswz));
        short8 a2 = *(const short8*)(ab + ((128u + 16u*g)  ^ aswz));
        short8 a3 = *(const short8*)(ab + ((192u + 16u*g)  ^ aswz));
        f32x4 acc = {0.f, 0.f, 0.f, 0.f};
        const char* wb = (const char*)Wt2 + ln * 256;
        acc = __builtin_amdgcn_mfma_f32_16x16x32_bf16(a0, *(const short8*)(wb + 16*g),       acc, 0, 0, 0);
        acc = __builtin_amdgcn_mfma_f32_16x16x32_bf16(a1, *(const short8*)(wb + 64 + 16*g),  acc, 0, 0, 0);
        acc = __builtin_amdgcn_mfma_f32_16x16x32_bf16(a2, *(const short8*)(wb + 128 + 16*g), acc, 0, 0, 0);
        acc = __builtin_amdgcn_mfma_f32_16x16x32_bf16(a3, *(const short8*)(wb + 192 + 16*g), acc, 0, 0, 0);

        float val[4];
        #pragma unroll
        for (int v = 0; v < 4; v++) {
            int row = m0 + 4*g + v;
            float logit = acc[v] + b2c + diffL[row*3 + ln];
            val[v] = (ln < 3) ? wgtL[row] / (1.f + expf(-logit)) : 0.f;
        }
        int r0t = ridL[m0], r15t = ridL[m0 + 15];
        if (r0t == r15t) {
            float s = val[0] + val[1] + val[2] + val[3];
            s += __shfl_xor(s, 16);
            s += __shfl_xor(s, 32);
            if (g == 0 && ln < 3) atomicAdd(out + 3*r0t + ln, s);
        } else if (ln < 3) {
            int rr = ridL[m0 + 4*g];
            float run = val[0];
            #pragma unroll
            for (int v = 1; v < 4; v++) {
                int rv = ridL[m0 + 4*g + v];
                if (rv == rr) run += val[v];
                else { atomicAdd(out + 3*rr + ln, run); run = val[v]; rr = rv; }
            }
            atomicAdd(out + 3*rr + ln, run);
        }
    }
}

extern "C" void kernel_launch(void* const* d_in, const int* in_sizes, int n_in,
                              void* d_out, int out_size, void* d_ws, size_t ws_size,
                              hipStream_t stream) {
    const float* dg  = (const float*)d_in[0];
    const float* k0  = (const float*)d_in[1];
    const float* xyz = (const float*)d_in[2];
    const float* vd  = (const float*)d_in[3];
    const float* W0  = (const float*)d_in[4];
    const float* b0  = (const float*)d_in[5];
    const float* W1  = (const float*)d_in[6];
    const float* b1  = (const float*)d_in[7];
    const float* W2  = (const float*)d_in[8];
    const float* b2  = (const float*)d_in[9];
    const int*   rid = (const int*)d_in[10];
    float* out = (float*)d_out;

    const int M = in_sizes[2] / 3;
    const int R = in_sizes[3] / 3;

    const size_t wtb    = (size_t)(128*64 + 128*128 + 16*128) * 2;
    const size_t vembsz = (size_t)R * 28 * 2;
    const size_t alogsz = (size_t)M * 8;
    const size_t wtssz  = (size_t)M * 4;
    const size_t stsz   = (size_t)(R + 1) * 4;
    const size_t recsz  = (size_t)M * 32;
    const size_t fixed  = wtb + vembsz + alogsz + wtssz + stsz + 1024;

    const size_t need64 = (size_t)NVOX * 64 + fixed + recsz;
    const size_t need32 = (size_t)NVOX * 32 + fixed + recsz;
    const size_t need24 = (size_t)NVOX * 24 + fixed + recsz;

    int tier = (ws_size >= need64) ? 64 : (ws_size >= need32) ? 32 :
               (ws_size >= need24) ? 24 : 0;
    const size_t gridb = (tier == 64) ? (size_t)NVOX*64 : (tier == 32) ? (size_t)NVOX*32 : (size_t)NVOX*24;

    char* w = (char*)d_ws;
    unsigned int*   gridp = (unsigned int*)w;   w += gridb;
    unsigned short* Wt0   = (unsigned short*)w; w += 128*64*2;
    unsigned short* Wt1   = (unsigned short*)w; w += 128*128*2;
    unsigned short* Wt2   = (unsigned short*)w; w += 16*128*2;
    unsigned short* vembb = (unsigned short*)w; w += vembsz;
    float2* alog  = (float2*)w;  w += alogsz;
    float*  wts   = (float*)w;   w += wtssz;
    int*    starts= (int*)w;     w += stsz;
    w = (char*)(((size_t)w + 255) & ~(size_t)255);
    u32x4*  rec   = (u32x4*)w;

    const int gb = (NVOX + 255) / 256;
    k_wprep <<<dim3(64), dim3(256), 0, stream>>>(W0, W1, W2, Wt0, Wt1, Wt2);
    k_starts<<<dim3((R + 256) / 256), dim3(256), 0, stream>>>(rid, starts, M, R);
    k_vdemb <<<dim3((R + 255) / 256), dim3(256), 0, stream>>>(vd, vembb, R);

    if (tier > 0) {
        if (tier == 64)      k_t64<<<dim3(gb), dim3(256), 0, stream>>>(k0, dg, gridp);
        else if (tier == 32) k_t32<<<dim3(gb), dim3(256), 0, stream>>>(k0, dg, gridp);
        else                 k_t24<<<dim3(gb), dim3(256), 0, stream>>>(k0, gridp);

        const int gblocks = (2 * M + 255) / 256;
        if (tier == 64)
            k_gather<64><<<dim3(gblocks), dim3(256), 0, stream>>>(gridp, dg, xyz, rec, alog, M);
        else if (tier == 32)
            k_gather<32><<<dim3(gblocks), dim3(256), 0, stream>>>(gridp, dg, xyz, rec, alog, M);
        else
            k_gather<24><<<dim3(gblocks), dim3(256), 0, stream>>>(gridp, dg, xyz, rec, alog, M);

        k_scanw<<<dim3(((size_t)R * 64 + 255) / 256), dim3(256), 0, stream>>>(alog, starts, wts, out, R);
        k_mlp_s<<<dim3((M + 127) / 128), dim3(256), 0, stream>>>(rec, rid, vembb, wts,
                                                                 Wt0, b0, Wt1, b1, Wt2, b2, out, M);
    } else {
        k_t24    <<<dim3(gb), dim3(256), 0, stream>>>(k0, gridp);
        k_densityC<<<dim3((M + 255) / 256), dim3(256), 0, stream>>>(dg, xyz, alog, M);
        k_scanw  <<<dim3(((size_t)R * 64 + 255) / 256), dim3(256), 0, stream>>>(alog, starts, wts, out, R);
        k_mlp_fused<<<dim3((M + 127) / 128), dim3(256), 0, stream>>>((const unsigned short*)gridp, xyz, rid, vembb, wts,
                                                                     Wt0, b0, Wt1, b1, Wt2, b2, out, M);
    }
}

// Round 5
// 613.414 us; speedup vs baseline: 5.7048x; 1.3998x over previous
//
#include <hip/hip_runtime.h>

#define ACT_SHIFT (-4.5951198501345898f)   // log(1/(1-0.01) - 1)
#define DELTA 0.5f
#define XS 25600                            // 160*160
#define YS 160
#define NVOX 4096000

typedef __attribute__((ext_vector_type(8))) short short8;
typedef __attribute__((ext_vector_type(4))) float f32x4;
typedef __attribute__((ext_vector_type(2))) unsigned int u32x2;
typedef __attribute__((ext_vector_type(4))) unsigned int u32x4;

__device__ __forceinline__ float softplusf(float x) {
    return x > 20.f ? x : log1pf(expf(x));
}
__device__ __forceinline__ unsigned short f2b(float x) {        // RNE (prep paths)
    unsigned int u = __float_as_uint(x);
    u += 0x7fffu + ((u >> 16) & 1u);
    return (unsigned short)(u >> 16);
}
__device__ __forceinline__ unsigned short f2b_fast(float x) {   // round-to-nearest, cheap
    return (unsigned short)((__float_as_uint(x) + 0x8000u) >> 16);
}
__device__ __forceinline__ float blo(unsigned int u) { return __uint_as_float(u << 16); }
__device__ __forceinline__ float bhi(unsigned int u) { return __uint_as_float(u & 0xffff0000u); }

__device__ __forceinline__ void trisetup(float px, float py, float pz,
                                         int& ix, int& iy, int& iz,
                                         float& fx, float& fy, float& fz) {
    float sx = (px + 1.f) * 0.5f * 159.f;
    float sy = (py + 1.f) * 0.5f * 159.f;
    float sz = (pz + 1.f) * 0.5f * 159.f;
    sx = fminf(fmaxf(sx, 0.f), 159.f);
    sy = fminf(fmaxf(sy, 0.f), 159.f);
    sz = fminf(fmaxf(sz, 0.f), 159.f);
    ix = (int)sx; if (ix > 158) ix = 158;
    iy = (int)sy; if (iy > 158) iy = 158;
    iz = (int)sz; if (iz > 158) iz = 158;
    fx = sx - (float)ix;
    fy = sy - (float)iy;
    fz = sz - (float)iz;
}

// ================= grid builders =================
// VOX64: entry(x,y,z) = {ch0..11(z) bf16, ch0..11(z+1) bf16, d(z) f32, d(z+1) f32, pad}
__global__ void k_t64(const float* __restrict__ k0, const float* __restrict__ dg,
                      unsigned int* __restrict__ grid) {
    int tid = blockIdx.x * 256 + threadIdx.x;
    if (tid >= NVOX) return;
    int z = tid % 160;
    int t1 = (z < 159) ? tid + 1 : tid;
    unsigned int w[16];
    #pragma unroll
    for (int j = 0; j < 6; j++) {
        w[j]   = (unsigned int)f2b(k0[(size_t)(2*j)*NVOX + tid]) | ((unsigned int)f2b(k0[(size_t)(2*j+1)*NVOX + tid]) << 16);
        w[6+j] = (unsigned int)f2b(k0[(size_t)(2*j)*NVOX + t1])  | ((unsigned int)f2b(k0[(size_t)(2*j+1)*NVOX + t1])  << 16);
    }
    w[12] = __float_as_uint(dg[tid]);
    w[13] = __float_as_uint(dg[t1]);
    w[14] = 0u; w[15] = 0u;
    u32x4* dst = (u32x4*)(grid + (size_t)tid * 16);
    dst[0] = *(u32x4*)(w);  dst[1] = *(u32x4*)(w+4);
    dst[2] = *(u32x4*)(w+8); dst[3] = *(u32x4*)(w+12);
}

// VOX32 / VOX24 fallbacks
__global__ void k_t32(const float* __restrict__ k0, const float* __restrict__ dg,
                      unsigned int* __restrict__ grid) {
    int tid = blockIdx.x * 256 + threadIdx.x;
    if (tid >= NVOX) return;
    unsigned int w[8];
    #pragma unroll
    for (int j = 0; j < 6; j++)
        w[j] = (unsigned int)f2b(k0[(size_t)(2*j)*NVOX + tid]) | ((unsigned int)f2b(k0[(size_t)(2*j+1)*NVOX + tid]) << 16);
    w[6] = __float_as_uint(dg[tid]);
    w[7] = 0u;
    u32x4* dst = (u32x4*)(grid + (size_t)tid * 8);
    dst[0] = *(u32x4*)(w); dst[1] = *(u32x4*)(w+4);
}
__global__ void k_t24(const float* __restrict__ k0, unsigned int* __restrict__ grid) {
    int tid = blockIdx.x * 256 + threadIdx.x;
    if (tid >= NVOX) return;
    unsigned int o[6];
    #pragma unroll
    for (int j = 0; j < 6; j++)
        o[j] = (unsigned int)f2b(k0[(size_t)(2*j)*NVOX + tid]) | ((unsigned int)f2b(k0[(size_t)(2*j+1)*NVOX + tid]) << 16);
    unsigned int* dst = grid + (size_t)tid * 6;
    #pragma unroll
    for (int j = 0; j < 6; j++) dst[j] = o[j];
}

// ================= small prep kernels =================
// Feature order (NEW): slots 0..26 = vd_emb, 27 = pad0, 28..36 = k0 ch3..11, 37..63 = 0
__global__ void k_wprep(const float* __restrict__ W0, const float* __restrict__ W1,
                        const float* __restrict__ W2,
                        unsigned short* __restrict__ Wt0, unsigned short* __restrict__ Wt1,
                        unsigned short* __restrict__ Wt2) {
    int id = blockIdx.x * 256 + threadIdx.x;
    if (id < 128 * 64) {
        int n = id >> 6, k = id & 63;
        float v = 0.f;
        if (k < 27)                 v = W0[(9 + k) * 128 + n];
        else if (k >= 28 && k < 37) v = W0[(k - 28) * 128 + n];
        Wt0[id] = f2b(v);
    }
    if (id < 128 * 128) { int n = id >> 7, k = id & 127; Wt1[id] = f2b(W1[k*128 + n]); }
    if (id < 16 * 128)  { int n = id >> 7, k = id & 127; Wt2[id] = (n < 3) ? f2b(W2[k*3 + n]) : 0; }
}

__global__ void k_starts(const int* __restrict__ rid, int* __restrict__ starts, int M, int R) {
    int r = blockIdx.x * blockDim.x + threadIdx.x;
    if (r > R) return;
    int lo = 0, hi = M;
    while (lo < hi) { int mid = (lo + hi) >> 1; if (rid[mid] < r) lo = mid + 1; else hi = mid; }
    starts[r] = lo;
}

__global__ void k_vdemb(const float* __restrict__ vd, unsigned short* __restrict__ emb, int R) {
    int r = blockIdx.x * blockDim.x + threadIdx.x;
    if (r >= R) return;
    float e[28];
    float v0 = vd[3*r], v1 = vd[3*r+1], v2 = vd[3*r+2];
    e[0] = v0; e[1] = v1; e[2] = v2;
    float v[3] = {v0, v1, v2};
    #pragma unroll
    for (int d = 0; d < 3; d++) {
        #pragma unroll
        for (int p = 0; p < 4; p++) {
            float a = v[d] * (float)(1 << p);
            e[3 + d*4 + p]  = sinf(a);
            e[15 + d*4 + p] = cosf(a);
        }
    }
    e[27] = 0.f;
    unsigned short* o = emb + r * 28;
    #pragma unroll
    for (int j = 0; j < 28; j++) o[j] = f2b(e[j]);
}

__global__ void k_densityC(const float* __restrict__ dg, const float* __restrict__ xyz,
                           float2* __restrict__ alog, int M) {
    int i = blockIdx.x * blockDim.x + threadIdx.x;
    if (i >= M) return;
    int ix, iy, iz; float fx, fy, fz;
    trisetup(xyz[3*i], xyz[3*i+1], xyz[3*i+2], ix, iy, iz, fx, fy, fz);
    const float* g = dg + ix * XS + iy * YS + iz;
    float gx = 1.f - fx, gy = 1.f - fy, gz = 1.f - fz;
    float v =
        gx * (gy * (gz * g[0]      + fz * g[1])      + fy * (gz * g[YS]      + fz * g[YS+1])) +
        fx * (gy * (gz * g[XS]     + fz * g[XS+1])   + fy * (gz * g[XS+YS]   + fz * g[XS+YS+1]));
    float sp = softplusf(v + ACT_SHIFT);
    float l  = -sp * DELTA;
    alog[i] = make_float2(1.f - expf(l), fmaxf(l, -15.9424285f));
}

// ================= gather: 2 threads/point =================
// rec[i] (32B): w0=(c3,c4) w1=(c5,c6) w2=(c7,c8) w3=(c9,c10) w4=(c11,0) w5..7=diff f32
template<int VOX>
__global__ __launch_bounds__(256) void k_gather(
    const unsigned int* __restrict__ grid, const float* __restrict__ dg,
    const float* __restrict__ xyz,
    u32x4* __restrict__ rec, float2* __restrict__ alog, int M) {

    const int t = blockIdx.x * 256 + threadIdx.x;
    const int p = t >> 1;
    const int dx = t & 1;
    if (p >= M) return;
    const int i = p;

    int ix, iy, iz; float fx, fy, fz;
    trisetup(xyz[3*i], xyz[3*i+1], xyz[3*i+2], ix, iy, iz, fx, fy, fz);
    float gz = 1.f - fz;
    float wx = dx ? fx : (1.f - fx);
    float wy[2] = {wx * (1.f - fy), wx * fy};

    float ch[12];
    #pragma unroll
    for (int c = 0; c < 12; c++) ch[c] = 0.f;
    float dd = 0.f;
    const int x = ix + dx;

    #pragma unroll
    for (int dy = 0; dy < 2; dy++) {
        float wc = wy[dy];
        size_t idx = (size_t)(x * 160 + (iy + dy)) * 160 + iz;
        if (VOX == 64) {
            const u32x4* e = (const u32x4*)(grid + idx * 16);
            u32x4 q0 = e[0], q1 = e[1], q2 = e[2], q3 = e[3];
            unsigned int wz[6]  = {q0[0],q0[1],q0[2],q0[3],q1[0],q1[1]};
            unsigned int wz1[6] = {q1[2],q1[3],q2[0],q2[1],q2[2],q2[3]};
            #pragma unroll
            for (int j = 0; j < 6; j++) {
                ch[2*j]   += wc * (gz * blo(wz[j]) + fz * blo(wz1[j]));
                ch[2*j+1] += wc * (gz * bhi(wz[j]) + fz * bhi(wz1[j]));
            }
            dd += wc * (gz * __uint_as_float(q3[0]) + fz * __uint_as_float(q3[1]));
        } else if (VOX == 32) {
            const u32x4* e0 = (const u32x4*)(grid + idx * 8);
            const u32x4* e1 = (const u32x4*)(grid + (idx + 1) * 8);
            u32x4 a0 = e0[0], a1 = e0[1], b0 = e1[0], b1 = e1[1];
            unsigned int wz[6]  = {a0[0],a0[1],a0[2],a0[3],a1[0],a1[1]};
            unsigned int wz1[6] = {b0[0],b0[1],b0[2],b0[3],b1[0],b1[1]};
            #pragma unroll
            for (int j = 0; j < 6; j++) {
                ch[2*j]   += wc * (gz * blo(wz[j]) + fz * blo(wz1[j]));
                ch[2*j+1] += wc * (gz * bhi(wz[j]) + fz * bhi(wz1[j]));
            }
            dd += wc * (gz * __uint_as_float(a1[2]) + fz * __uint_as_float(b1[2]));
        } else {
            const u32x2* e = (const u32x2*)(grid + idx * 6);
            u32x2 a0 = e[0], a1 = e[1], a2 = e[2], a3 = e[3], a4 = e[4], a5 = e[5];
            unsigned int wz[6]  = {a0[0],a0[1],a1[0],a1[1],a2[0],a2[1]};
            unsigned int wz1[6] = {a3[0],a3[1],a4[0],a4[1],a5[0],a5[1]};
            #pragma unroll
            for (int j = 0; j < 6; j++) {
                ch[2*j]   += wc * (gz * blo(wz[j]) + fz * blo(wz1[j]));
                ch[2*j+1] += wc * (gz * bhi(wz[j]) + fz * bhi(wz1[j]));
            }
            const float* dr = dg + (size_t)(x * 160 + (iy + dy)) * 160 + iz;
            dd += wc * (gz * dr[0] + fz * dr[1]);
        }
    }

    #pragma unroll
    for (int c = 0; c < 12; c++) ch[c] += __shfl_xor(ch[c], 1);
    dd += __shfl_xor(dd, 1);

    if (dx == 0) {
        unsigned int w[8];
        w[0] = (unsigned int)f2b(ch[3]) | ((unsigned int)f2b(ch[4]) << 16);
        w[1] = (unsigned int)f2b(ch[5]) | ((unsigned int)f2b(ch[6]) << 16);
        w[2] = (unsigned int)f2b(ch[7]) | ((unsigned int)f2b(ch[8]) << 16);
        w[3] = (unsigned int)f2b(ch[9]) | ((unsigned int)f2b(ch[10]) << 16);
        w[4] = (unsigned int)f2b(ch[11]);
        w[5] = __float_as_uint(ch[0]);
        w[6] = __float_as_uint(ch[1]);
        w[7] = __float_as_uint(ch[2]);
        rec[(size_t)i*2]     = *(u32x4*)(w);
        rec[(size_t)i*2 + 1] = *(u32x4*)(w + 4);
    } else {
        float sp = softplusf(dd + ACT_SHIFT);
        float l  = -sp * DELTA;
        alog[i] = make_float2(1.f - expf(l), fmaxf(l, -15.9424285f));
    }
}

// ================= wave-per-ray scan =================
__global__ void k_scanw(const float2* __restrict__ alog, const int* __restrict__ starts,
                        float* __restrict__ wts, float* __restrict__ out, int R) {
    const int r = (blockIdx.x * blockDim.x + threadIdx.x) >> 6;
    const int lane = threadIdx.x & 63;
    if (r >= R) return;
    const int s = starts[r], e = starts[r + 1];
    float carry = 0.f;
    for (int i0 = s; i0 < e; i0 += 64) {
        int idx = i0 + lane;
        bool pr = idx < e;
        float a = 0.f, x = 0.f;
        if (pr) { float2 v = alog[idx]; a = v.x; x = v.y; }
        float incl = x;
        #pragma unroll
        for (int d = 1; d < 64; d <<= 1) {
            float tv = __shfl_up(incl, d);
            if (lane >= d) incl += tv;
        }
        if (pr) wts[idx] = a * expf(carry + (incl - x));
        carry += __shfl(incl, 63);
    }
    float ainv = expf(carry);
    if (lane == 0) { out[3*r] = ainv; out[3*r+1] = ainv; out[3*r+2] = ainv; }
}

// ================= MFMA MLP with register-hoisted weights =================
__global__ __launch_bounds__(256, 2) void k_mlp_s(
    const u32x4* __restrict__ rec, const int* __restrict__ rid,
    const unsigned short* __restrict__ vemb, const float* __restrict__ wts,
    const unsigned short* __restrict__ Wt0, const float* __restrict__ b0,
    const unsigned short* __restrict__ Wt1, const float* __restrict__ b1,
    const unsigned short* __restrict__ Wt2, const float* __restrict__ b2,
    float* __restrict__ out, int M) {

    __shared__ char featL[128 * 128];
    __shared__ char hL[128 * 256];
    __shared__ float diffL[128 * 3];
    __shared__ float wgtL[128];
    __shared__ int   ridL[128];

    const int t = threadIdx.x;
    const int base = blockIdx.x * 128;

    if (t < 128) {
        const int i = base + t;
        unsigned int fr[32];
        #pragma unroll
        for (int j = 19; j < 32; j++) fr[j] = 0u;
        float wpt = 0.f; int r = 0;
        float d0 = 0.f, d1 = 0.f, d2 = 0.f;
        if (i < M) {
            u32x4 r0 = rec[(size_t)i*2];
            u32x4 r1 = rec[(size_t)i*2 + 1];
            r = rid[i];
            wpt = wts[i];
            const unsigned int* vp = (const unsigned int*)(vemb + (size_t)r * 28);
            #pragma unroll
            for (int j = 0; j < 14; j++) fr[j] = vp[j];   // vemb (slot 27 pad=0)
            fr[14] = r0[0]; fr[15] = r0[1]; fr[16] = r0[2]; fr[17] = r0[3];
            fr[18] = r1[0] & 0xffffu;                      // (c11, 0)
            d0 = __uint_as_float(r1[1]); d1 = __uint_as_float(r1[2]); d2 = __uint_as_float(r1[3]);
        } else {
            #pragma unroll
            for (int j = 0; j < 19; j++) fr[j] = 0u;
        }
        diffL[t*3 + 0] = d0; diffL[t*3 + 1] = d1; diffL[t*3 + 2] = d2;
        wgtL[t] = wpt;
        ridL[t] = r;
        char* fp = featL + t * 128;
        unsigned int rs = (unsigned int)((t & 7) << 4);
        #pragma unroll
        for (int j = 0; j < 8; j++)
            *(u32x4*)(fp + ((16u*j) ^ rs)) = *(u32x4*)(fr + 4*j);
    }
    __syncthreads();

    const int lane = t & 63;
    const int w = t >> 6;
    const int g = lane >> 4;
    const int ln = lane & 15;

    // ---- layer 1: hoisted B-frags + biases ----
    {
        short8 B1[16];
        float bias0[8];
        #pragma unroll
        for (int nt = 0; nt < 8; nt++) {
            const char* wb = (const char*)Wt0 + (nt*16 + ln) * 128 + 16*g;
            B1[2*nt]   = *(const short8*)(wb);
            B1[2*nt+1] = *(const short8*)(wb + 64);
            bias0[nt]  = b0[nt*16 + ln];
        }
        #pragma unroll
        for (int mi = 0; mi < 2; mi++) {
            const int m0 = 32*w + 16*mi;
            const int arow = m0 + ln;
            const unsigned int aswz = (unsigned int)((arow & 7) << 4);
            const char* ab = featL + arow * 128;
            short8 a0 = *(const short8*)(ab + ((16u*g)        ^ aswz));
            short8 a1 = *(const short8*)(ab + ((64u + 16u*g)  ^ aswz));
            #pragma unroll
            for (int nt = 0; nt < 8; nt++) {
                f32x4 acc = {bias0[nt], bias0[nt], bias0[nt], bias0[nt]};
                acc = __builtin_amdgcn_mfma_f32_16x16x32_bf16(a0, B1[2*nt],   acc, 0, 0, 0);
                acc = __builtin_amdgcn_mfma_f32_16x16x32_bf16(a1, B1[2*nt+1], acc, 0, 0, 0);
                #pragma unroll
                for (int v = 0; v < 4; v++) {
                    int row = m0 + 4*g + v;
                    unsigned short hv = f2b_fast(fmaxf(acc[v], 0.f));
                    *(unsigned short*)(hL + (((unsigned)(row*256 + (nt*16+ln)*2)) ^ ((unsigned)((row & 7) << 4)))) = hv;
                }
            }
        }
    }

    // ---- layer 2: hoisted 32 B-frags ----
    {
        short8 B2[32];
        float bias1[8];
        #pragma unroll
        for (int nt = 0; nt < 8; nt++) {
            const char* wb = (const char*)Wt1 + (nt*16 + ln) * 256 + 16*g;
            #pragma unroll
            for (int kk = 0; kk < 4; kk++)
                B2[nt*4 + kk] = *(const short8*)(wb + 64*kk);
            bias1[nt] = b1[nt*16 + ln];
        }
        #pragma unroll
        for (int mi = 0; mi < 2; mi++) {
            const int m0 = 32*w + 16*mi;
            const int arow = m0 + ln;
            const unsigned int aswz = (unsigned int)((arow & 7) << 4);
            const char* ab = hL + arow * 256;
            short8 a0 = *(const short8*)(ab + ((16u*g)         ^ aswz));
            short8 a1 = *(const short8*)(ab + ((64u  + 16u*g)  ^ aswz));
            short8 a2 = *(const short8*)(ab + ((128u + 16u*g)  ^ aswz));
            short8 a3 = *(const short8*)(ab + ((192u + 16u*g)  ^ aswz));
            #pragma unroll
            for (int nt = 0; nt < 8; nt++) {
                f32x4 acc = {bias1[nt], bias1[nt], bias1[nt], bias1[nt]};
                acc = __builtin_amdgcn_mfma_f32_16x16x32_bf16(a0, B2[nt*4+0], acc, 0, 0, 0);
                acc = __builtin_amdgcn_mfma_f32_16x16x32_bf16(a1, B2[nt*4+1], acc, 0, 0, 0);
                acc = __builtin_amdgcn_mfma_f32_16x16x32_bf16(a2, B2[nt*4+2], acc, 0, 0, 0);
                acc = __builtin_amdgcn_mfma_f32_16x16x32_bf16(a3, B2[nt*4+3], acc, 0, 0, 0);
                #pragma unroll
                for (int v = 0; v < 4; v++) {
                    int row = m0 + 4*g + v;
                    unsigned short hv = f2b_fast(fmaxf(acc[v], 0.f));
                    *(unsigned short*)(hL + (((unsigned)(row*256 + (nt*16+ln)*2)) ^ ((unsigned)((row & 7) << 4)))) = hv;
                }
            }
        }
    }

    // ---- layer 3 + sigmoid + ray-merged atomics ----
    {
        short8 B3[4];
        const char* wb = (const char*)Wt2 + ln * 256 + 16*g;
        #pragma unroll
        for (int kk = 0; kk < 4; kk++) B3[kk] = *(const short8*)(wb + 64*kk);
        const float b2c = (ln < 3) ? b2[ln] : 0.f;

        #pragma unroll
        for (int mi = 0; mi < 2; mi++) {
            const int m0 = 32*w + 16*mi;
            const int arow = m0 + ln;
            const unsigned int aswz = (unsigned int)((arow & 7) << 4);
            const char* ab = hL + arow * 256;
            short8 a0 = *(const short8*)(ab + ((16u*g)         ^ aswz));
            short8 a1 = *(const short8*)(ab + ((64u  + 16u*g)  ^ aswz));
            short8 a2 = *(const short8*)(ab + ((128u + 16u*g)  ^ aswz));
            short8 a3 = *(const short8*)(ab + ((192u + 16u*g)  ^ aswz));
            f32x4 acc = {0.f, 0.f, 0.f, 0.f};
            acc = __builtin_amdgcn_mfma_f32_16x16x32_bf16(a0, B3[0], acc, 0, 0, 0);
            acc = __builtin_amdgcn_mfma_f32_16x16x32_bf16(a1, B3[1], acc, 0, 0, 0);
            acc = __builtin_amdgcn_mfma_f32_16x16x32_bf16(a2, B3[2], acc, 0, 0, 0);
            acc = __builtin_amdgcn_mfma_f32_16x16x32_bf16(a3, B3[3], acc, 0, 0, 0);

            float val[4];
            #pragma unroll
            for (int v = 0; v < 4; v++) {
                int row = m0 + 4*g + v;
                float logit = acc[v] + b2c + diffL[row*3 + ln];
                val[v] = (ln < 3) ? wgtL[row] / (1.f + expf(-logit)) : 0.f;
            }
            int r0t = ridL[m0], r15t = ridL[m0 + 15];
            if (r0t == r15t) {
                float s = val[0] + val[1] + val[2] + val[3];
                s += __shfl_xor(s, 16);
                s += __shfl_xor(s, 32);
                if (g == 0 && ln < 3) atomicAdd(out + 3*r0t + ln, s);
            } else if (ln < 3) {
                int rr = ridL[m0 + 4*g];
                float run = val[0];
                #pragma unroll
                for (int v = 1; v < 4; v++) {
                    int rv = ridL[m0 + 4*g + v];
                    if (rv == rr) run += val[v];
                    else { atomicAdd(out + 3*rr + ln, run); run = val[v]; rr = rv; }
                }
                atomicAdd(out + 3*rr + ln, run);
            }
        }
    }
}

// ================= legacy fused MLP (ultra fallback, 24B grid) =================
__global__ __launch_bounds__(256) void k_mlp_fused(
    const unsigned short* __restrict__ k0b, const float* __restrict__ xyz,
    const int* __restrict__ rid, const unsigned short* __restrict__ vemb,
    const float* __restrict__ wts,
    const unsigned short* __restrict__ Wt0, const float* __restrict__ b0,
    const unsigned short* __restrict__ Wt1, const float* __restrict__ b1,
    const unsigned short* __restrict__ Wt2, const float* __restrict__ b2,
    float* __restrict__ out, int M) {

    __shared__ char featL[128 * 128];
    __shared__ char hL[128 * 256];
    __shared__ float diffL[128 * 3];
    __shared__ float wgtL[128];
    __shared__ int   ridL[128];

    const int t = threadIdx.x;
    const int base = blockIdx.x * 128;
    const int p = t >> 1;
    const int dx = t & 1;
    const int i = base + p;

    float ch[12];
    #pragma unroll
    for (int c = 0; c < 12; c++) ch[c] = 0.f;

    if (i < M) {
        int ix, iy, iz; float fx, fy, fz;
        trisetup(xyz[3*i], xyz[3*i+1], xyz[3*i+2], ix, iy, iz, fx, fy, fz);
        float gz = 1.f - fz;
        float wx = dx ? fx : (1.f - fx);
        float wy0 = wx * (1.f - fy), wy1 = wx * fy;
        #pragma unroll
        for (int dy = 0; dy < 2; dy++) {
            float w2 = dy ? wy1 : wy0;
            size_t vox = (size_t)((ix + dx) * 160 + (iy + dy)) * 160 + iz;
            const char* pv = (const char*)k0b + vox * 24;
            u32x2 a0 = *(const u32x2*)(pv);
            u32x2 a1 = *(const u32x2*)(pv + 8);
            u32x2 a2 = *(const u32x2*)(pv + 16);
            u32x2 a3 = *(const u32x2*)(pv + 24);
            u32x2 a4 = *(const u32x2*)(pv + 32);
            u32x2 a5 = *(const u32x2*)(pv + 40);
            unsigned int u0[6] = {a0[0],a0[1],a1[0],a1[1],a2[0],a2[1]};
            unsigned int u1[6] = {a3[0],a3[1],a4[0],a4[1],a5[0],a5[1]};
            #pragma unroll
            for (int j = 0; j < 6; j++) {
                ch[2*j]   += w2 * (gz * blo(u0[j]) + fz * blo(u1[j]));
                ch[2*j+1] += w2 * (gz * bhi(u0[j]) + fz * bhi(u1[j]));
            }
        }
    }
    #pragma unroll
    for (int c = 0; c < 12; c++) ch[c] += __shfl_xor(ch[c], 1);

    if (dx == 0) {
        unsigned int fr[32];
        #pragma unroll
        for (int j = 19; j < 32; j++) fr[j] = 0u;
        float wpt = 0.f; int r = 0;
        if (i < M) {
            r = rid[i];
            wpt = wts[i];
            const unsigned int* vp = (const unsigned int*)(vemb + (size_t)r * 28);
            #pragma unroll
            for (int j = 0; j < 14; j++) fr[j] = vp[j];
            fr[14] = (unsigned int)f2b(ch[3]) | ((unsigned int)f2b(ch[4]) << 16);
            fr[15] = (unsigned int)f2b(ch[5]) | ((unsigned int)f2b(ch[6]) << 16);
            fr[16] = (unsigned int)f2b(ch[7]) | ((unsigned int)f2b(ch[8]) << 16);
            fr[17] = (unsigned int)f2b(ch[9]) | ((unsigned int)f2b(ch[10]) << 16);
            fr[18] = (unsigned int)f2b(ch[11]);
        } else {
            #pragma unroll
            for (int j = 0; j < 19; j++) fr[j] = 0u;
        }
        diffL[p*3 + 0] = ch[0];
        diffL[p*3 + 1] = ch[1];
        diffL[p*3 + 2] = ch[2];
        wgtL[p] = wpt;
        ridL[p] = r;
        char* fp = featL + p * 128;
        unsigned int rs = (unsigned int)((p & 7) << 4);
        #pragma unroll
        for (int j = 0; j < 8; j++)
            *(u32x4*)(fp + ((16u*j) ^ rs)) = *(u32x4*)(fr + 4*j);
    }
    __syncthreads();

    const int lane = t & 63;
    const int w = t >> 6;
    const int g = lane >> 4;
    const int ln = lane & 15;

    #pragma unroll
    for (int mi = 0; mi < 2; mi++) {
        const int m0 = 32*w + 16*mi;
        const int arow = m0 + ln;
        const unsigned int aswz = (unsigned int)((arow & 7) << 4);
        const char* ab = featL + arow * 128;
        short8 a0 = *(const short8*)(ab + ((16u*g)        ^ aswz));
        short8 a1 = *(const short8*)(ab + ((64u + 16u*g)  ^ aswz));
        #pragma unroll
        for (int nt = 0; nt < 8; nt++) {
            const int n0 = 16 * nt;
            float bias = b0[n0 + ln];
            f32x4 acc = {bias, bias, bias, bias};
            const char* wb = (const char*)Wt0 + (n0 + ln) * 128;
            acc = __builtin_amdgcn_mfma_f32_16x16x32_bf16(a0, *(const short8*)(wb + 16*g),      acc, 0, 0, 0);
            acc = __builtin_amdgcn_mfma_f32_16x16x32_bf16(a1, *(const short8*)(wb + 64 + 16*g), acc, 0, 0, 0);
            #pragma unroll
            for (int v = 0; v < 4; v++) {
                int row = m0 + 4*g + v;
                unsigned short hv = f2b_fast(fmaxf(acc[v], 0.f));
                *(unsigned short*)(hL + (((unsigned)(row*256 + (n0+ln)*2)) ^ ((unsigned)((row & 7) << 4)))) = hv;
            }
        }
    }

    #pragma unroll
    for (int mi = 0; mi < 2; mi++) {
        const int m0 = 32*w + 16*mi;
        const int arow = m0 + ln;
        const unsigned int aswz = (unsigned int)((arow & 7) << 4);
        const char* ab = hL + arow * 256;
        short8 a0 = *(const short8*)(ab + ((16u*g)         ^ aswz));
        short8 a1 = *(const short8*)(ab + ((64u  + 16u*g)  ^ aswz));
        short8 a2 = *(const short8*)(ab + ((128u + 16u*g)  ^ aswz));
        short8 a3 = *(const short8*)(ab + ((192u + 16u*g)  ^ aswz));
        #pragma unroll
        for (int nt = 0; nt < 8; nt++) {
            const int n0 = 16 * nt;
            float bias = b1[n0 + ln];
            f32x4 acc = {bias, bias, bias, bias};
            const char* wb = (const char*)Wt1 + (n0 + ln) * 256;
            acc = __builtin_amdgcn_mfma_f32_16x16x32_bf16(a0, *(const short8*)(wb + 16*g),       acc, 0, 0, 0);
            acc = __builtin_amdgcn_mfma_f32_16x16x32_bf16(a1, *(const short8*)(wb + 64 + 16*g),  acc, 0, 0, 0);
            acc = __builtin_amdgcn_mfma_f32_16x16x32_bf16(a2, *(const short8*)(wb + 128 + 16*g), acc, 0, 0, 0);
            acc = __builtin_amdgcn_mfma_f32_16x16x32_bf16(a3, *(const short8*)(wb + 192 + 16*g), acc, 0, 0, 0);
            #pragma unroll
            for (int v = 0; v < 4; v++) {
                int row = m0 + 4*g + v;
                unsigned short hv = f2b_fast(fmaxf(acc[v], 0.f));
                *(unsigned short*)(hL + (((unsigned)(row*256 + (n0+ln)*2)) ^ ((unsigned)((row & 7) << 4)))) = hv;
            }
        }
    }

    const float b2c = (ln < 3) ? b2[ln] : 0.f;
    #pragma unroll
    for (int mi = 0; mi < 2; mi++) {
        const int m0 = 32*w + 16*mi;
        const int arow = m0 + ln;
        const unsigned int aswz = (unsigned int)((arow & 7) << 4);
        const char* ab = hL + arow * 256;
        short8 a0 = *(const short8*)(ab + ((16u*g)         ^ aswz));
        short8 a1 = *(const short8*)(ab + ((64u  + 16u*g)  ^ aswz));
        short8 a2 = *(const short8*)(ab + ((128u + 16u*g)  ^ aswz));
        short8 a3 = *(const short8*)(ab + ((192u + 16u*g)  ^ aswz));
        f32x4 acc = {0.f, 0.f, 0.f, 0.f};
        const char* wb = (const char*)Wt2 + ln * 256;
        acc = __builtin_amdgcn_mfma_f32_16x16x32_bf16(a0, *(const short8*)(wb + 16*g),       acc, 0, 0, 0);
        acc = __builtin_amdgcn_mfma_f32_16x16x32_bf16(a1, *(const short8*)(wb + 64 + 16*g),  acc, 0, 0, 0);
        acc = __builtin_amdgcn_mfma_f32_16x16x32_bf16(a2, *(const short8*)(wb + 128 + 16*g), acc, 0, 0, 0);
        acc = __builtin_amdgcn_mfma_f32_16x16x32_bf16(a3, *(const short8*)(wb + 192 + 16*g), acc, 0, 0, 0);

        float val[4];
        #pragma unroll
        for (int v = 0; v < 4; v++) {
            int row = m0 + 4*g + v;
            float logit = acc[v] + b2c + diffL[row*3 + ln];
            val[v] = (ln < 3) ? wgtL[row] / (1.f + expf(-logit)) : 0.f;
        }
        int r0t = ridL[m0], r15t = ridL[m0 + 15];
        if (r0t == r15t) {
            float s = val[0] + val[1] + val[2] + val[3];
            s += __shfl_xor(s, 16);
            s += __shfl_xor(s, 32);
            if (g == 0 && ln < 3) atomicAdd(out + 3*r0t + ln, s);
        } else if (ln < 3) {
            int rr = ridL[m0 + 4*g];
            float run = val[0];
            #pragma unroll
            for (int v = 1; v < 4; v++) {
                int rv = ridL[m0 + 4*g + v];
                if (rv == rr) run += val[v];
                else { atomicAdd(out + 3*rr + ln, run); run = val[v]; rr = rv; }
            }
            atomicAdd(out + 3*rr + ln, run);
        }
    }
}

extern "C" void kernel_launch(void* const* d_in, const int* in_sizes, int n_in,
                              void* d_out, int out_size, void* d_ws, size_t ws_size,
                              hipStream_t stream) {
    const float* dg  = (const float*)d_in[0];
    const float* k0  = (const float*)d_in[1];
    const float* xyz = (const float*)d_in[2];
    const float* vd  = (const float*)d_in[3];
    const float* W0  = (const float*)d_in[4];
    const float* b0  = (const float*)d_in[5];
    const float* W1  = (const float*)d_in[6];
    const float* b1  = (const float*)d_in[7];
    const float* W2  = (const float*)d_in[8];
    const float* b2  = (const float*)d_in[9];
    const int*   rid = (const int*)d_in[10];
    float* out = (float*)d_out;

    const int M = in_sizes[2] / 3;
    const int R = in_sizes[3] / 3;

    const size_t wtb    = (size_t)(128*64 + 128*128 + 16*128) * 2;
    const size_t vembsz = (size_t)R * 28 * 2;
    const size_t alogsz = (size_t)M * 8;
    const size_t wtssz  = (size_t)M * 4;
    const size_t stsz   = (size_t)(R + 1) * 4;
    const size_t recsz  = (size_t)M * 32;
    const size_t fixed  = wtb + vembsz + alogsz + wtssz + stsz + 1024;

    const size_t need64 = (size_t)NVOX * 64 + fixed + recsz;
    const size_t need32 = (size_t)NVOX * 32 + fixed + recsz;
    const size_t need24 = (size_t)NVOX * 24 + fixed + recsz;

    int tier = (ws_size >= need64) ? 64 : (ws_size >= need32) ? 32 :
               (ws_size >= need24) ? 24 : 0;
    const size_t gridb = (tier == 64) ? (size_t)NVOX*64 : (tier == 32) ? (size_t)NVOX*32 : (size_t)NVOX*24;

    char* w = (char*)d_ws;
    unsigned int*   gridp = (unsigned int*)w;   w += gridb;
    unsigned short* Wt0   = (unsigned short*)w; w += 128*64*2;
    unsigned short* Wt1   = (unsigned short*)w; w += 128*128*2;
    unsigned short* Wt2   = (unsigned short*)w; w += 16*128*2;
    unsigned short* vembb = (unsigned short*)w; w += vembsz;
    float2* alog  = (float2*)w;  w += alogsz;
    float*  wts   = (float*)w;   w += wtssz;
    int*    starts= (int*)w;     w += stsz;
    w = (char*)(((size_t)w + 255) & ~(size_t)255);
    u32x4*  rec   = (u32x4*)w;

    const int gb = (NVOX + 255) / 256;
    k_wprep <<<dim3(64), dim3(256), 0, stream>>>(W0, W1, W2, Wt0, Wt1, Wt2);
    k_starts<<<dim3((R + 256) / 256), dim3(256), 0, stream>>>(rid, starts, M, R);
    k_vdemb <<<dim3((R + 255) / 256), dim3(256), 0, stream>>>(vd, vembb, R);

    if (tier > 0) {
        if (tier == 64)      k_t64<<<dim3(gb), dim3(256), 0, stream>>>(k0, dg, gridp);
        else if (tier == 32) k_t32<<<dim3(gb), dim3(256), 0, stream>>>(k0, dg, gridp);
        else                 k_t24<<<dim3(gb), dim3(256), 0, stream>>>(k0, gridp);

        const int gblocks = (2 * M + 255) / 256;
        if (tier == 64)
            k_gather<64><<<dim3(gblocks), dim3(256), 0, stream>>>(gridp, dg, xyz, rec, alog, M);
        else if (tier == 32)
            k_gather<32><<<dim3(gblocks), dim3(256), 0, stream>>>(gridp, dg, xyz, rec, alog, M);
        else
            k_gather<24><<<dim3(gblocks), dim3(256), 0, stream>>>(gridp, dg, xyz, rec, alog, M);

        k_scanw<<<dim3(((size_t)R * 64 + 255) / 256), dim3(256), 0, stream>>>(alog, starts, wts, out, R);
        k_mlp_s<<<dim3((M + 127) / 128), dim3(256), 0, stream>>>(rec, rid, vembb, wts,
                                                                 Wt0, b0, Wt1, b1, Wt2, b2, out, M);
    } else {
        k_t24    <<<dim3(gb), dim3(256), 0, stream>>>(k0, gridp);
        k_densityC<<<dim3((M + 255) / 256), dim3(256), 0, stream>>>(dg, xyz, alog, M);
        k_scanw  <<<dim3(((size_t)R * 64 + 255) / 256), dim3(256), 0, stream>>>(alog, starts, wts, out, R);
        k_mlp_fused<<<dim3((M + 127) / 128), dim3(256), 0, stream>>>((const unsigned short*)gridp, xyz, rid, vembb, wts,
                                                                     Wt0, b0, Wt1, b1, Wt2, b2, out, M);
    }
}

// Round 6
// 494.642 us; speedup vs baseline: 7.0746x; 1.2401x over previous
//
#include <hip/hip_runtime.h>

#define ACT_SHIFT (-4.5951198501345898f)   // log(1/(1-0.01) - 1)
#define DELTA 0.5f
#define XS 25600                            // 160*160
#define YS 160
#define NVOX 4096000

typedef __attribute__((ext_vector_type(8))) short short8;
typedef __attribute__((ext_vector_type(4))) float f32x4;
typedef __attribute__((ext_vector_type(2))) unsigned int u32x2;
typedef __attribute__((ext_vector_type(4))) unsigned int u32x4;

__device__ __forceinline__ float softplusf(float x) {
    return x > 20.f ? x : log1pf(expf(x));
}
__device__ __forceinline__ unsigned short f2b(float x) {        // RNE (prep paths)
    unsigned int u = __float_as_uint(x);
    u += 0x7fffu + ((u >> 16) & 1u);
    return (unsigned short)(u >> 16);
}
__device__ __forceinline__ unsigned short f2b_fast(float x) {   // round-to-nearest, cheap
    return (unsigned short)((__float_as_uint(x) + 0x8000u) >> 16);
}
__device__ __forceinline__ float blo(unsigned int u) { return __uint_as_float(u << 16); }
__device__ __forceinline__ float bhi(unsigned int u) { return __uint_as_float(u & 0xffff0000u); }

__device__ __forceinline__ void trisetup(float px, float py, float pz,
                                         int& ix, int& iy, int& iz,
                                         float& fx, float& fy, float& fz) {
    float sx = (px + 1.f) * 0.5f * 159.f;
    float sy = (py + 1.f) * 0.5f * 159.f;
    float sz = (pz + 1.f) * 0.5f * 159.f;
    sx = fminf(fmaxf(sx, 0.f), 159.f);
    sy = fminf(fmaxf(sy, 0.f), 159.f);
    sz = fminf(fmaxf(sz, 0.f), 159.f);
    ix = (int)sx; if (ix > 158) ix = 158;
    iy = (int)sy; if (iy > 158) iy = 158;
    iz = (int)sz; if (iz > 158) iz = 158;
    fx = sx - (float)ix;
    fy = sy - (float)iy;
    fz = sz - (float)iz;
}

// ================= grid builders =================
// VOX64: entry(x,y,z) = {ch0..11(z) bf16, ch0..11(z+1) bf16, d(z) f32, d(z+1) f32, pad}
__global__ void k_t64(const float* __restrict__ k0, const float* __restrict__ dg,
                      unsigned int* __restrict__ grid) {
    int tid = blockIdx.x * 256 + threadIdx.x;
    if (tid >= NVOX) return;
    int z = tid % 160;
    int t1 = (z < 159) ? tid + 1 : tid;
    unsigned int w[16];
    #pragma unroll
    for (int j = 0; j < 6; j++) {
        w[j]   = (unsigned int)f2b(k0[(size_t)(2*j)*NVOX + tid]) | ((unsigned int)f2b(k0[(size_t)(2*j+1)*NVOX + tid]) << 16);
        w[6+j] = (unsigned int)f2b(k0[(size_t)(2*j)*NVOX + t1])  | ((unsigned int)f2b(k0[(size_t)(2*j+1)*NVOX + t1])  << 16);
    }
    w[12] = __float_as_uint(dg[tid]);
    w[13] = __float_as_uint(dg[t1]);
    w[14] = 0u; w[15] = 0u;
    u32x4* dst = (u32x4*)(grid + (size_t)tid * 16);
    dst[0] = *(u32x4*)(w);  dst[1] = *(u32x4*)(w+4);
    dst[2] = *(u32x4*)(w+8); dst[3] = *(u32x4*)(w+12);
}

// VOX32 / VOX24 fallbacks
__global__ void k_t32(const float* __restrict__ k0, const float* __restrict__ dg,
                      unsigned int* __restrict__ grid) {
    int tid = blockIdx.x * 256 + threadIdx.x;
    if (tid >= NVOX) return;
    unsigned int w[8];
    #pragma unroll
    for (int j = 0; j < 6; j++)
        w[j] = (unsigned int)f2b(k0[(size_t)(2*j)*NVOX + tid]) | ((unsigned int)f2b(k0[(size_t)(2*j+1)*NVOX + tid]) << 16);
    w[6] = __float_as_uint(dg[tid]);
    w[7] = 0u;
    u32x4* dst = (u32x4*)(grid + (size_t)tid * 8);
    dst[0] = *(u32x4*)(w); dst[1] = *(u32x4*)(w+4);
}
__global__ void k_t24(const float* __restrict__ k0, unsigned int* __restrict__ grid) {
    int tid = blockIdx.x * 256 + threadIdx.x;
    if (tid >= NVOX) return;
    unsigned int o[6];
    #pragma unroll
    for (int j = 0; j < 6; j++)
        o[j] = (unsigned int)f2b(k0[(size_t)(2*j)*NVOX + tid]) | ((unsigned int)f2b(k0[(size_t)(2*j+1)*NVOX + tid]) << 16);
    unsigned int* dst = grid + (size_t)tid * 6;
    #pragma unroll
    for (int j = 0; j < 6; j++) dst[j] = o[j];
}

// ================= small prep kernels =================
// Feature order: slots 0..26 = vd_emb, 27 = pad0, 28..36 = k0 ch3..11, 37..63 = 0
__global__ void k_wprep(const float* __restrict__ W0, const float* __restrict__ W1,
                        const float* __restrict__ W2,
                        unsigned short* __restrict__ Wt0, unsigned short* __restrict__ Wt1,
                        unsigned short* __restrict__ Wt2) {
    int id = blockIdx.x * 256 + threadIdx.x;
    if (id < 128 * 64) {
        int n = id >> 6, k = id & 63;
        float v = 0.f;
        if (k < 27)                 v = W0[(9 + k) * 128 + n];
        else if (k >= 28 && k < 37) v = W0[(k - 28) * 128 + n];
        Wt0[id] = f2b(v);
    }
    if (id < 128 * 128) { int n = id >> 7, k = id & 127; Wt1[id] = f2b(W1[k*128 + n]); }
    if (id < 16 * 128)  { int n = id >> 7, k = id & 127; Wt2[id] = (n < 3) ? f2b(W2[k*3 + n]) : 0; }
}

__global__ void k_starts(const int* __restrict__ rid, int* __restrict__ starts, int M, int R) {
    int r = blockIdx.x * blockDim.x + threadIdx.x;
    if (r > R) return;
    int lo = 0, hi = M;
    while (lo < hi) { int mid = (lo + hi) >> 1; if (rid[mid] < r) lo = mid + 1; else hi = mid; }
    starts[r] = lo;
}

__global__ void k_vdemb(const float* __restrict__ vd, unsigned short* __restrict__ emb, int R) {
    int r = blockIdx.x * blockDim.x + threadIdx.x;
    if (r >= R) return;
    float e[28];
    float v0 = vd[3*r], v1 = vd[3*r+1], v2 = vd[3*r+2];
    e[0] = v0; e[1] = v1; e[2] = v2;
    float v[3] = {v0, v1, v2};
    #pragma unroll
    for (int d = 0; d < 3; d++) {
        #pragma unroll
        for (int p = 0; p < 4; p++) {
            float a = v[d] * (float)(1 << p);
            e[3 + d*4 + p]  = sinf(a);
            e[15 + d*4 + p] = cosf(a);
        }
    }
    e[27] = 0.f;
    unsigned short* o = emb + r * 28;
    #pragma unroll
    for (int j = 0; j < 28; j++) o[j] = f2b(e[j]);
}

__global__ void k_densityC(const float* __restrict__ dg, const float* __restrict__ xyz,
                           float2* __restrict__ alog, int M) {
    int i = blockIdx.x * blockDim.x + threadIdx.x;
    if (i >= M) return;
    int ix, iy, iz; float fx, fy, fz;
    trisetup(xyz[3*i], xyz[3*i+1], xyz[3*i+2], ix, iy, iz, fx, fy, fz);
    const float* g = dg + ix * XS + iy * YS + iz;
    float gx = 1.f - fx, gy = 1.f - fy, gz = 1.f - fz;
    float v =
        gx * (gy * (gz * g[0]      + fz * g[1])      + fy * (gz * g[YS]      + fz * g[YS+1])) +
        fx * (gy * (gz * g[XS]     + fz * g[XS+1])   + fy * (gz * g[XS+YS]   + fz * g[XS+YS+1]));
    float sp = softplusf(v + ACT_SHIFT);
    float l  = -sp * DELTA;
    alog[i] = make_float2(1.f - expf(l), fmaxf(l, -15.9424285f));
}

// ================= gather: 2 threads/point =================
// rec[i] (32B): w0=(c3,c4) w1=(c5,c6) w2=(c7,c8) w3=(c9,c10) w4=(c11,0) w5..7=diff f32
template<int VOX>
__global__ __launch_bounds__(256) void k_gather(
    const unsigned int* __restrict__ grid, const float* __restrict__ dg,
    const float* __restrict__ xyz,
    u32x4* __restrict__ rec, float2* __restrict__ alog, int M) {

    const int t = blockIdx.x * 256 + threadIdx.x;
    const int p = t >> 1;
    const int dx = t & 1;
    if (p >= M) return;
    const int i = p;

    int ix, iy, iz; float fx, fy, fz;
    trisetup(xyz[3*i], xyz[3*i+1], xyz[3*i+2], ix, iy, iz, fx, fy, fz);
    float gz = 1.f - fz;
    float wx = dx ? fx : (1.f - fx);
    float wy[2] = {wx * (1.f - fy), wx * fy};

    float ch[12];
    #pragma unroll
    for (int c = 0; c < 12; c++) ch[c] = 0.f;
    float dd = 0.f;
    const int x = ix + dx;

    #pragma unroll
    for (int dy = 0; dy < 2; dy++) {
        float wc = wy[dy];
        size_t idx = (size_t)(x * 160 + (iy + dy)) * 160 + iz;
        if (VOX == 64) {
            const u32x4* e = (const u32x4*)(grid + idx * 16);
            u32x4 q0 = e[0], q1 = e[1], q2 = e[2], q3 = e[3];
            unsigned int wz[6]  = {q0[0],q0[1],q0[2],q0[3],q1[0],q1[1]};
            unsigned int wz1[6] = {q1[2],q1[3],q2[0],q2[1],q2[2],q2[3]};
            #pragma unroll
            for (int j = 0; j < 6; j++) {
                ch[2*j]   += wc * (gz * blo(wz[j]) + fz * blo(wz1[j]));
                ch[2*j+1] += wc * (gz * bhi(wz[j]) + fz * bhi(wz1[j]));
            }
            dd += wc * (gz * __uint_as_float(q3[0]) + fz * __uint_as_float(q3[1]));
        } else if (VOX == 32) {
            const u32x4* e0 = (const u32x4*)(grid + idx * 8);
            const u32x4* e1 = (const u32x4*)(grid + (idx + 1) * 8);
            u32x4 a0 = e0[0], a1 = e0[1], b0 = e1[0], b1 = e1[1];
            unsigned int wz[6]  = {a0[0],a0[1],a0[2],a0[3],a1[0],a1[1]};
            unsigned int wz1[6] = {b0[0],b0[1],b0[2],b0[3],b1[0],b1[1]};
            #pragma unroll
            for (int j = 0; j < 6; j++) {
                ch[2*j]   += wc * (gz * blo(wz[j]) + fz * blo(wz1[j]));
                ch[2*j+1] += wc * (gz * bhi(wz[j]) + fz * bhi(wz1[j]));
            }
            dd += wc * (gz * __uint_as_float(a1[2]) + fz * __uint_as_float(b1[2]));
        } else {
            const u32x2* e = (const u32x2*)(grid + idx * 6);
            u32x2 a0 = e[0], a1 = e[1], a2 = e[2], a3 = e[3], a4 = e[4], a5 = e[5];
            unsigned int wz[6]  = {a0[0],a0[1],a1[0],a1[1],a2[0],a2[1]};
            unsigned int wz1[6] = {a3[0],a3[1],a4[0],a4[1],a5[0],a5[1]};
            #pragma unroll
            for (int j = 0; j < 6; j++) {
                ch[2*j]   += wc * (gz * blo(wz[j]) + fz * blo(wz1[j]));
                ch[2*j+1] += wc * (gz * bhi(wz[j]) + fz * bhi(wz1[j]));
            }
            const float* dr = dg + (size_t)(x * 160 + (iy + dy)) * 160 + iz;
            dd += wc * (gz * dr[0] + fz * dr[1]);
        }
    }

    #pragma unroll
    for (int c = 0; c < 12; c++) ch[c] += __shfl_xor(ch[c], 1);
    dd += __shfl_xor(dd, 1);

    if (dx == 0) {
        unsigned int w[8];
        w[0] = (unsigned int)f2b(ch[3]) | ((unsigned int)f2b(ch[4]) << 16);
        w[1] = (unsigned int)f2b(ch[5]) | ((unsigned int)f2b(ch[6]) << 16);
        w[2] = (unsigned int)f2b(ch[7]) | ((unsigned int)f2b(ch[8]) << 16);
        w[3] = (unsigned int)f2b(ch[9]) | ((unsigned int)f2b(ch[10]) << 16);
        w[4] = (unsigned int)f2b(ch[11]);
        w[5] = __float_as_uint(ch[0]);
        w[6] = __float_as_uint(ch[1]);
        w[7] = __float_as_uint(ch[2]);
        rec[(size_t)i*2]     = *(u32x4*)(w);
        rec[(size_t)i*2 + 1] = *(u32x4*)(w + 4);
    } else {
        float sp = softplusf(dd + ACT_SHIFT);
        float l  = -sp * DELTA;
        alog[i] = make_float2(1.f - expf(l), fmaxf(l, -15.9424285f));
    }
}

// ================= wave-per-ray scan =================
__global__ void k_scanw(const float2* __restrict__ alog, const int* __restrict__ starts,
                        float* __restrict__ wts, float* __restrict__ out, int R) {
    const int r = (blockIdx.x * blockDim.x + threadIdx.x) >> 6;
    const int lane = threadIdx.x & 63;
    if (r >= R) return;
    const int s = starts[r], e = starts[r + 1];
    float carry = 0.f;
    for (int i0 = s; i0 < e; i0 += 64) {
        int idx = i0 + lane;
        bool pr = idx < e;
        float a = 0.f, x = 0.f;
        if (pr) { float2 v = alog[idx]; a = v.x; x = v.y; }
        float incl = x;
        #pragma unroll
        for (int d = 1; d < 64; d <<= 1) {
            float tv = __shfl_up(incl, d);
            if (lane >= d) incl += tv;
        }
        if (pr) wts[idx] = a * expf(carry + (incl - x));
        carry += __shfl(incl, 63);
    }
    float ainv = expf(carry);
    if (lane == 0) { out[3*r] = ainv; out[3*r+1] = ainv; out[3*r+2] = ainv; }
}

// ================= MFMA MLP: N-split waves, fully hoisted weights =================
// Wave w computes output cols [32w,32w+32) of L1/L2 for ALL 128 rows; L3 is M-split.
__global__ __launch_bounds__(256, 3) void k_mlp_s(
    const u32x4* __restrict__ rec, const int* __restrict__ rid,
    const unsigned short* __restrict__ vemb, const float* __restrict__ wts,
    const unsigned short* __restrict__ Wt0, const float* __restrict__ b0,
    const unsigned short* __restrict__ Wt1, const float* __restrict__ b1,
    const unsigned short* __restrict__ Wt2, const float* __restrict__ b2,
    float* __restrict__ out, int M) {

    __shared__ char featL[128 * 128];
    __shared__ char hL[128 * 256];
    __shared__ float diffL[128 * 3];
    __shared__ float wgtL[128];
    __shared__ int   ridL[128];

    const int t = threadIdx.x;
    const int base = blockIdx.x * 128;

    if (t < 128) {
        const int i = base + t;
        unsigned int fr[32];
        #pragma unroll
        for (int j = 19; j < 32; j++) fr[j] = 0u;
        float wpt = 0.f; int r = 0;
        float d0 = 0.f, d1 = 0.f, d2 = 0.f;
        if (i < M) {
            u32x4 r0 = rec[(size_t)i*2];
            u32x4 r1 = rec[(size_t)i*2 + 1];
            r = rid[i];
            wpt = wts[i];
            const unsigned int* vp = (const unsigned int*)(vemb + (size_t)r * 28);
            #pragma unroll
            for (int j = 0; j < 14; j++) fr[j] = vp[j];   // vemb (slot 27 pad=0)
            fr[14] = r0[0]; fr[15] = r0[1]; fr[16] = r0[2]; fr[17] = r0[3];
            fr[18] = r1[0] & 0xffffu;                      // (c11, 0)
            d0 = __uint_as_float(r1[1]); d1 = __uint_as_float(r1[2]); d2 = __uint_as_float(r1[3]);
        } else {
            #pragma unroll
            for (int j = 0; j < 19; j++) fr[j] = 0u;
        }
        diffL[t*3 + 0] = d0; diffL[t*3 + 1] = d1; diffL[t*3 + 2] = d2;
        wgtL[t] = wpt;
        ridL[t] = r;
        char* fp = featL + t * 128;
        unsigned int rs = (unsigned int)((t & 7) << 4);
        #pragma unroll
        for (int j = 0; j < 8; j++)
            *(u32x4*)(fp + ((16u*j) ^ rs)) = *(u32x4*)(fr + 4*j);
    }

    const int lane = t & 63;
    const int w = t >> 6;
    const int g = lane >> 4;
    const int ln = lane & 15;

    // ---- hoist ALL L1/L2 weight fragments for this wave's N-slice (once) ----
    short8 B1[2][2], B2[2][4];
    float bias0[2], bias1[2];
    #pragma unroll
    for (int ntl = 0; ntl < 2; ntl++) {
        const int n0 = (2*w + ntl) * 16;
        const char* wb0 = (const char*)Wt0 + (n0 + ln) * 128 + 16*g;
        B1[ntl][0] = *(const short8*)(wb0);
        B1[ntl][1] = *(const short8*)(wb0 + 64);
        bias0[ntl] = b0[n0 + ln];
        const char* wb1 = (const char*)Wt1 + (n0 + ln) * 256 + 16*g;
        #pragma unroll
        for (int kk = 0; kk < 4; kk++)
            B2[ntl][kk] = *(const short8*)(wb1 + 64*kk);
        bias1[ntl] = b1[n0 + ln];
    }
    __syncthreads();   // feat ready

    // ---- layer 1: all 8 m-tiles, this wave's 2 n-tiles ----
    #pragma unroll
    for (int mt = 0; mt < 8; mt++) {
        const int arow = mt*16 + ln;
        const unsigned int aswz = (unsigned int)((arow & 7) << 4);
        const char* ab = featL + arow * 128;
        short8 a0 = *(const short8*)(ab + ((16u*g)        ^ aswz));
        short8 a1 = *(const short8*)(ab + ((64u + 16u*g)  ^ aswz));
        #pragma unroll
        for (int ntl = 0; ntl < 2; ntl++) {
            const int n0 = (2*w + ntl) * 16;
            f32x4 acc = {bias0[ntl], bias0[ntl], bias0[ntl], bias0[ntl]};
            acc = __builtin_amdgcn_mfma_f32_16x16x32_bf16(a0, B1[ntl][0], acc, 0, 0, 0);
            acc = __builtin_amdgcn_mfma_f32_16x16x32_bf16(a1, B1[ntl][1], acc, 0, 0, 0);
            #pragma unroll
            for (int v = 0; v < 4; v++) {
                int row = mt*16 + 4*g + v;
                unsigned short hv = f2b_fast(fmaxf(acc[v], 0.f));
                *(unsigned short*)(hL + (((unsigned)(row*256 + (n0+ln)*2)) ^ ((unsigned)((row & 7) << 4)))) = hv;
            }
        }
    }
    __syncthreads();   // h1 complete

    // ---- layer 2: reads of all h1 rows -> acc in regs; stores deferred past barrier ----
    f32x4 acc2[8][2];
    #pragma unroll
    for (int mt = 0; mt < 8; mt++) {
        const int arow = mt*16 + ln;
        const unsigned int aswz = (unsigned int)((arow & 7) << 4);
        const char* ab = hL + arow * 256;
        short8 a0 = *(const short8*)(ab + ((16u*g)         ^ aswz));
        short8 a1 = *(const short8*)(ab + ((64u  + 16u*g)  ^ aswz));
        short8 a2 = *(const short8*)(ab + ((128u + 16u*g)  ^ aswz));
        short8 a3 = *(const short8*)(ab + ((192u + 16u*g)  ^ aswz));
        #pragma unroll
        for (int ntl = 0; ntl < 2; ntl++) {
            f32x4 acc = {bias1[ntl], bias1[ntl], bias1[ntl], bias1[ntl]};
            acc = __builtin_amdgcn_mfma_f32_16x16x32_bf16(a0, B2[ntl][0], acc, 0, 0, 0);
            acc = __builtin_amdgcn_mfma_f32_16x16x32_bf16(a1, B2[ntl][1], acc, 0, 0, 0);
            acc = __builtin_amdgcn_mfma_f32_16x16x32_bf16(a2, B2[ntl][2], acc, 0, 0, 0);
            acc = __builtin_amdgcn_mfma_f32_16x16x32_bf16(a3, B2[ntl][3], acc, 0, 0, 0);
            acc2[mt][ntl] = acc;
        }
    }
    __syncthreads();   // all h1 reads done -> safe to overwrite in place
    #pragma unroll
    for (int mt = 0; mt < 8; mt++) {
        #pragma unroll
        for (int ntl = 0; ntl < 2; ntl++) {
            const int n0 = (2*w + ntl) * 16;
            #pragma unroll
            for (int v = 0; v < 4; v++) {
                int row = mt*16 + 4*g + v;
                unsigned short hv = f2b_fast(fmaxf(acc2[mt][ntl][v], 0.f));
                *(unsigned short*)(hL + (((unsigned)(row*256 + (n0+ln)*2)) ^ ((unsigned)((row & 7) << 4)))) = hv;
            }
        }
    }
    __syncthreads();   // h2 complete

    // ---- layer 3 (M-split: rows 32w..32w+31) + sigmoid + ray-merged atomics ----
    {
        short8 B3[4];
        const char* wb2 = (const char*)Wt2 + ln * 256 + 16*g;
        #pragma unroll
        for (int kk = 0; kk < 4; kk++) B3[kk] = *(const short8*)(wb2 + 64*kk);
        const float b2c = (ln < 3) ? b2[ln] : 0.f;

        #pragma unroll
        for (int mi = 0; mi < 2; mi++) {
            const int m0 = 32*w + 16*mi;
            const int arow = m0 + ln;
            const unsigned int aswz = (unsigned int)((arow & 7) << 4);
            const char* ab = hL + arow * 256;
            short8 a0 = *(const short8*)(ab + ((16u*g)         ^ aswz));
            short8 a1 = *(const short8*)(ab + ((64u  + 16u*g)  ^ aswz));
            short8 a2 = *(const short8*)(ab + ((128u + 16u*g)  ^ aswz));
            short8 a3 = *(const short8*)(ab + ((192u + 16u*g)  ^ aswz));
            f32x4 acc = {0.f, 0.f, 0.f, 0.f};
            acc = __builtin_amdgcn_mfma_f32_16x16x32_bf16(a0, B3[0], acc, 0, 0, 0);
            acc = __builtin_amdgcn_mfma_f32_16x16x32_bf16(a1, B3[1], acc, 0, 0, 0);
            acc = __builtin_amdgcn_mfma_f32_16x16x32_bf16(a2, B3[2], acc, 0, 0, 0);
            acc = __builtin_amdgcn_mfma_f32_16x16x32_bf16(a3, B3[3], acc, 0, 0, 0);

            float val[4];
            #pragma unroll
            for (int v = 0; v < 4; v++) {
                int row = m0 + 4*g + v;
                float logit = acc[v] + b2c + diffL[row*3 + ln];
                val[v] = (ln < 3) ? wgtL[row] / (1.f + expf(-logit)) : 0.f;
            }
            int r0t = ridL[m0], r15t = ridL[m0 + 15];
            if (r0t == r15t) {
                float s = val[0] + val[1] + val[2] + val[3];
                s += __shfl_xor(s, 16);
                s += __shfl_xor(s, 32);
                if (g == 0 && ln < 3) atomicAdd(out + 3*r0t + ln, s);
            } else if (ln < 3) {
                int rr = ridL[m0 + 4*g];
                float run = val[0];
                #pragma unroll
                for (int v = 1; v < 4; v++) {
                    int rv = ridL[m0 + 4*g + v];
                    if (rv == rr) run += val[v];
                    else { atomicAdd(out + 3*rr + ln, run); run = val[v]; rr = rv; }
                }
                atomicAdd(out + 3*rr + ln, run);
            }
        }
    }
}

// ================= legacy fused MLP (ultra fallback, 24B grid) =================
__global__ __launch_bounds__(256) void k_mlp_fused(
    const unsigned short* __restrict__ k0b, const float* __restrict__ xyz,
    const int* __restrict__ rid, const unsigned short* __restrict__ vemb,
    const float* __restrict__ wts,
    const unsigned short* __restrict__ Wt0, const float* __restrict__ b0,
    const unsigned short* __restrict__ Wt1, const float* __restrict__ b1,
    const unsigned short* __restrict__ Wt2, const float* __restrict__ b2,
    float* __restrict__ out, int M) {

    __shared__ char featL[128 * 128];
    __shared__ char hL[128 * 256];
    __shared__ float diffL[128 * 3];
    __shared__ float wgtL[128];
    __shared__ int   ridL[128];

    const int t = threadIdx.x;
    const int base = blockIdx.x * 128;
    const int p = t >> 1;
    const int dx = t & 1;
    const int i = base + p;

    float ch[12];
    #pragma unroll
    for (int c = 0; c < 12; c++) ch[c] = 0.f;

    if (i < M) {
        int ix, iy, iz; float fx, fy, fz;
        trisetup(xyz[3*i], xyz[3*i+1], xyz[3*i+2], ix, iy, iz, fx, fy, fz);
        float gz = 1.f - fz;
        float wx = dx ? fx : (1.f - fx);
        float wy0 = wx * (1.f - fy), wy1 = wx * fy;
        #pragma unroll
        for (int dy = 0; dy < 2; dy++) {
            float w2 = dy ? wy1 : wy0;
            size_t vox = (size_t)((ix + dx) * 160 + (iy + dy)) * 160 + iz;
            const char* pv = (const char*)k0b + vox * 24;
            u32x2 a0 = *(const u32x2*)(pv);
            u32x2 a1 = *(const u32x2*)(pv + 8);
            u32x2 a2 = *(const u32x2*)(pv + 16);
            u32x2 a3 = *(const u32x2*)(pv + 24);
            u32x2 a4 = *(const u32x2*)(pv + 32);
            u32x2 a5 = *(const u32x2*)(pv + 40);
            unsigned int u0[6] = {a0[0],a0[1],a1[0],a1[1],a2[0],a2[1]};
            unsigned int u1[6] = {a3[0],a3[1],a4[0],a4[1],a5[0],a5[1]};
            #pragma unroll
            for (int j = 0; j < 6; j++) {
                ch[2*j]   += w2 * (gz * blo(u0[j]) + fz * blo(u1[j]));
                ch[2*j+1] += w2 * (gz * bhi(u0[j]) + fz * bhi(u1[j]));
            }
        }
    }
    #pragma unroll
    for (int c = 0; c < 12; c++) ch[c] += __shfl_xor(ch[c], 1);

    if (dx == 0) {
        unsigned int fr[32];
        #pragma unroll
        for (int j = 19; j < 32; j++) fr[j] = 0u;
        float wpt = 0.f; int r = 0;
        if (i < M) {
            r = rid[i];
            wpt = wts[i];
            const unsigned int* vp = (const unsigned int*)(vemb + (size_t)r * 28);
            #pragma unroll
            for (int j = 0; j < 14; j++) fr[j] = vp[j];
            fr[14] = (unsigned int)f2b(ch[3]) | ((unsigned int)f2b(ch[4]) << 16);
            fr[15] = (unsigned int)f2b(ch[5]) | ((unsigned int)f2b(ch[6]) << 16);
            fr[16] = (unsigned int)f2b(ch[7]) | ((unsigned int)f2b(ch[8]) << 16);
            fr[17] = (unsigned int)f2b(ch[9]) | ((unsigned int)f2b(ch[10]) << 16);
            fr[18] = (unsigned int)f2b(ch[11]);
        } else {
            #pragma unroll
            for (int j = 0; j < 19; j++) fr[j] = 0u;
        }
        diffL[p*3 + 0] = ch[0];
        diffL[p*3 + 1] = ch[1];
        diffL[p*3 + 2] = ch[2];
        wgtL[p] = wpt;
        ridL[p] = r;
        char* fp = featL + p * 128;
        unsigned int rs = (unsigned int)((p & 7) << 4);
        #pragma unroll
        for (int j = 0; j < 8; j++)
            *(u32x4*)(fp + ((16u*j) ^ rs)) = *(u32x4*)(fr + 4*j);
    }
    __syncthreads();

    const int lane = t & 63;
    const int w = t >> 6;
    const int g = lane >> 4;
    const int ln = lane & 15;

    #pragma unroll
    for (int mi = 0; mi < 2; mi++) {
        const int m0 = 32*w + 16*mi;
        const int arow = m0 + ln;
        const unsigned int aswz = (unsigned int)((arow & 7) << 4);
        const char* ab = featL + arow * 128;
        short8 a0 = *(const short8*)(ab + ((16u*g)        ^ aswz));
        short8 a1 = *(const short8*)(ab + ((64u + 16u*g)  ^ aswz));
        #pragma unroll
        for (int nt = 0; nt < 8; nt++) {
            const int n0 = 16 * nt;
            float bias = b0[n0 + ln];
            f32x4 acc = {bias, bias, bias, bias};
            const char* wb = (const char*)Wt0 + (n0 + ln) * 128;
            acc = __builtin_amdgcn_mfma_f32_16x16x32_bf16(a0, *(const short8*)(wb + 16*g),      acc, 0, 0, 0);
            acc = __builtin_amdgcn_mfma_f32_16x16x32_bf16(a1, *(const short8*)(wb + 64 + 16*g), acc, 0, 0, 0);
            #pragma unroll
            for (int v = 0; v < 4; v++) {
                int row = m0 + 4*g + v;
                unsigned short hv = f2b_fast(fmaxf(acc[v], 0.f));
                *(unsigned short*)(hL + (((unsigned)(row*256 + (n0+ln)*2)) ^ ((unsigned)((row & 7) << 4)))) = hv;
            }
        }
    }

    #pragma unroll
    for (int mi = 0; mi < 2; mi++) {
        const int m0 = 32*w + 16*mi;
        const int arow = m0 + ln;
        const unsigned int aswz = (unsigned int)((arow & 7) << 4);
        const char* ab = hL + arow * 256;
        short8 a0 = *(const short8*)(ab + ((16u*g)         ^ aswz));
        short8 a1 = *(const short8*)(ab + ((64u  + 16u*g)  ^ aswz));
        short8 a2 = *(const short8*)(ab + ((128u + 16u*g)  ^ aswz));
        short8 a3 = *(const short8*)(ab + ((192u + 16u*g)  ^ aswz));
        #pragma unroll
        for (int nt = 0; nt < 8; nt++) {
            const int n0 = 16 * nt;
            float bias = b1[n0 + ln];
            f32x4 acc = {bias, bias, bias, bias};
            const char* wb = (const char*)Wt1 + (n0 + ln) * 256;
            acc = __builtin_amdgcn_mfma_f32_16x16x32_bf16(a0, *(const short8*)(wb + 16*g),       acc, 0, 0, 0);
            acc = __builtin_amdgcn_mfma_f32_16x16x32_bf16(a1, *(const short8*)(wb + 64 + 16*g),  acc, 0, 0, 0);
            acc = __builtin_amdgcn_mfma_f32_16x16x32_bf16(a2, *(const short8*)(wb + 128 + 16*g), acc, 0, 0, 0);
            acc = __builtin_amdgcn_mfma_f32_16x16x32_bf16(a3, *(const short8*)(wb + 192 + 16*g), acc, 0, 0, 0);
            #pragma unroll
            for (int v = 0; v < 4; v++) {
                int row = m0 + 4*g + v;
                unsigned short hv = f2b_fast(fmaxf(acc[v], 0.f));
                *(unsigned short*)(hL + (((unsigned)(row*256 + (n0+ln)*2)) ^ ((unsigned)((row & 7) << 4)))) = hv;
            }
        }
    }

    const float b2c = (ln < 3) ? b2[ln] : 0.f;
    #pragma unroll
    for (int mi = 0; mi < 2; mi++) {
        const int m0 = 32*w + 16*mi;
        const int arow = m0 + ln;
        const unsigned int aswz = (unsigned int)((arow & 7) << 4);
        const char* ab = hL + arow * 256;
        short8 a0 = *(const short8*)(ab + ((16u*g)         ^ aswz));
        short8 a1 = *(const short8*)(ab + ((64u  + 16u*g)  ^ aswz));
        short8 a2 = *(const short8*)(ab + ((128u + 16u*g)  ^ aswz));
        short8 a3 = *(const short8*)(ab + ((192u + 16u*g)  ^ aswz));
        f32x4 acc = {0.f, 0.f, 0.f, 0.f};
        const char* wb = (const char*)Wt2 + ln * 256;
        acc = __builtin_amdgcn_mfma_f32_16x16x32_bf16(a0, *(const short8*)(wb + 16*g),       acc, 0, 0, 0);
        acc = __builtin_amdgcn_mfma_f32_16x16x32_bf16(a1, *(const short8*)(wb + 64 + 16*g),  acc, 0, 0, 0);
        acc = __builtin_amdgcn_mfma_f32_16x16x32_bf16(a2, *(const short8*)(wb + 128 + 16*g), acc, 0, 0, 0);
        acc = __builtin_amdgcn_mfma_f32_16x16x32_bf16(a3, *(const short8*)(wb + 192 + 16*g), acc, 0, 0, 0);

        float val[4];
        #pragma unroll
        for (int v = 0; v < 4; v++) {
            int row = m0 + 4*g + v;
            float logit = acc[v] + b2c + diffL[row*3 + ln];
            val[v] = (ln < 3) ? wgtL[row] / (1.f + expf(-logit)) : 0.f;
        }
        int r0t = ridL[m0], r15t = ridL[m0 + 15];
        if (r0t == r15t) {
            float s = val[0] + val[1] + val[2] + val[3];
            s += __shfl_xor(s, 16);
            s += __shfl_xor(s, 32);
            if (g == 0 && ln < 3) atomicAdd(out + 3*r0t + ln, s);
        } else if (ln < 3) {
            int rr = ridL[m0 + 4*g];
            float run = val[0];
            #pragma unroll
            for (int v = 1; v < 4; v++) {
                int rv = ridL[m0 + 4*g + v];
                if (rv == rr) run += val[v];
                else { atomicAdd(out + 3*rr + ln, run); run = val[v]; rr = rv; }
            }
            atomicAdd(out + 3*rr + ln, run);
        }
    }
}

extern "C" void kernel_launch(void* const* d_in, const int* in_sizes, int n_in,
                              void* d_out, int out_size, void* d_ws, size_t ws_size,
                              hipStream_t stream) {
    const float* dg  = (const float*)d_in[0];
    const float* k0  = (const float*)d_in[1];
    const float* xyz = (const float*)d_in[2];
    const float* vd  = (const float*)d_in[3];
    const float* W0  = (const float*)d_in[4];
    const float* b0  = (const float*)d_in[5];
    const float* W1  = (const float*)d_in[6];
    const float* b1  = (const float*)d_in[7];
    const float* W2  = (const float*)d_in[8];
    const float* b2  = (const float*)d_in[9];
    const int*   rid = (const int*)d_in[10];
    float* out = (float*)d_out;

    const int M = in_sizes[2] / 3;
    const int R = in_sizes[3] / 3;

    const size_t wtb    = (size_t)(128*64 + 128*128 + 16*128) * 2;
    const size_t vembsz = (size_t)R * 28 * 2;
    const size_t alogsz = (size_t)M * 8;
    const size_t wtssz  = (size_t)M * 4;
    const size_t stsz   = (size_t)(R + 1) * 4;
    const size_t recsz  = (size_t)M * 32;
    const size_t fixed  = wtb + vembsz + alogsz + wtssz + stsz + 1024;

    const size_t need64 = (size_t)NVOX * 64 + fixed + recsz;
    const size_t need32 = (size_t)NVOX * 32 + fixed + recsz;
    const size_t need24 = (size_t)NVOX * 24 + fixed + recsz;

    int tier = (ws_size >= need64) ? 64 : (ws_size >= need32) ? 32 :
               (ws_size >= need24) ? 24 : 0;
    const size_t gridb = (tier == 64) ? (size_t)NVOX*64 : (tier == 32) ? (size_t)NVOX*32 : (size_t)NVOX*24;

    char* w = (char*)d_ws;
    unsigned int*   gridp = (unsigned int*)w;   w += gridb;
    unsigned short* Wt0   = (unsigned short*)w; w += 128*64*2;
    unsigned short* Wt1   = (unsigned short*)w; w += 128*128*2;
    unsigned short* Wt2   = (unsigned short*)w; w += 16*128*2;
    unsigned short* vembb = (unsigned short*)w; w += vembsz;
    float2* alog  = (float2*)w;  w += alogsz;
    float*  wts   = (float*)w;   w += wtssz;
    int*    starts= (int*)w;     w += stsz;
    w = (char*)(((size_t)w + 255) & ~(size_t)255);
    u32x4*  rec   = (u32x4*)w;

    const int gb = (NVOX + 255) / 256;
    k_wprep <<<dim3(64), dim3(256), 0, stream>>>(W0, W1, W2, Wt0, Wt1, Wt2);
    k_starts<<<dim3((R + 256) / 256), dim3(256), 0, stream>>>(rid, starts, M, R);
    k_vdemb <<<dim3((R + 255) / 256), dim3(256), 0, stream>>>(vd, vembb, R);

    if (tier > 0) {
        if (tier == 64)      k_t64<<<dim3(gb), dim3(256), 0, stream>>>(k0, dg, gridp);
        else if (tier == 32) k_t32<<<dim3(gb), dim3(256), 0, stream>>>(k0, dg, gridp);
        else                 k_t24<<<dim3(gb), dim3(256), 0, stream>>>(k0, gridp);

        const int gblocks = (2 * M + 255) / 256;
        if (tier == 64)
            k_gather<64><<<dim3(gblocks), dim3(256), 0, stream>>>(gridp, dg, xyz, rec, alog, M);
        else if (tier == 32)
            k_gather<32><<<dim3(gblocks), dim3(256), 0, stream>>>(gridp, dg, xyz, rec, alog, M);
        else
            k_gather<24><<<dim3(gblocks), dim3(256), 0, stream>>>(gridp, dg, xyz, rec, alog, M);

        k_scanw<<<dim3(((size_t)R * 64 + 255) / 256), dim3(256), 0, stream>>>(alog, starts, wts, out, R);
        k_mlp_s<<<dim3((M + 127) / 128), dim3(256), 0, stream>>>(rec, rid, vembb, wts,
                                                                 Wt0, b0, Wt1, b1, Wt2, b2, out, M);
    } else {
        k_t24    <<<dim3(gb), dim3(256), 0, stream>>>(k0, gridp);
        k_densityC<<<dim3((M + 255) / 256), dim3(256), 0, stream>>>(dg, xyz, alog, M);
        k_scanw  <<<dim3(((size_t)R * 64 + 255) / 256), dim3(256), 0, stream>>>(alog, starts, wts, out, R);
        k_mlp_fused<<<dim3((M + 127) / 128), dim3(256), 0, stream>>>((const unsigned short*)gridp, xyz, rid, vembb, wts,
                                                                     Wt0, b0, Wt1, b1, Wt2, b2, out, M);
    }
}